// Round 6
// baseline (2537.621 us; speedup 1.0000x reference)
//
#include <hip/hip_runtime.h>
#include <cstddef>

// Problem dims
#define B_  64
#define R_  49
#define F_  512
#define H_  512
#define V_  10000
#define TT  32
#define TS  31

typedef _Float16 half8 __attribute__((ext_vector_type(8)));
typedef float    f32x4 __attribute__((ext_vector_type(4)));

__device__ __forceinline__ float fsigm(float x) { return 1.0f / (1.0f + __expf(-x)); }
__device__ __forceinline__ float ftanh(float x) { return 1.0f - 2.0f / (__expf(2.0f * x) + 1.0f); }

// ---------------------------------------------------------------------------
// Generic fp32 NT GEMM (pre-phase only)
// ---------------------------------------------------------------------------
__global__ __launch_bounds__(256) void gemm_nt_f32(
    const float* __restrict__ A, int lda,
    const float* __restrict__ Bm, int ldb,
    const float* __restrict__ bias1, const float* __restrict__ bias2,
    float* __restrict__ C, int ldc, int M, int N, int K)
{
    __shared__ __align__(16) float As[16][68];
    __shared__ __align__(16) float Bs[16][68];
    const int tid = threadIdx.x;
    const int m0 = blockIdx.y * 64, n0 = blockIdx.x * 64;
    const int tr = tid >> 4, tc = tid & 15;
    const int lrow = tid >> 2, lk4 = (tid & 3) * 4;
    const bool am = (m0 + lrow) < M;
    const bool bn = (n0 + lrow) < N;
    const float* aptr = A + (size_t)(m0 + lrow) * lda + lk4;
    const float* bptr = Bm + (size_t)(n0 + lrow) * ldb + lk4;
    float acc[4][4] = {};

    for (int k0 = 0; k0 < K; k0 += 16) {
        float4 av = make_float4(0.f, 0.f, 0.f, 0.f);
        float4 bv = make_float4(0.f, 0.f, 0.f, 0.f);
        if (am) av = *(const float4*)(aptr + k0);
        if (bn) bv = *(const float4*)(bptr + k0);
        __syncthreads();
        As[lk4 + 0][lrow] = av.x; As[lk4 + 1][lrow] = av.y;
        As[lk4 + 2][lrow] = av.z; As[lk4 + 3][lrow] = av.w;
        Bs[lk4 + 0][lrow] = bv.x; Bs[lk4 + 1][lrow] = bv.y;
        Bs[lk4 + 2][lrow] = bv.z; Bs[lk4 + 3][lrow] = bv.w;
        __syncthreads();
#pragma unroll
        for (int kk = 0; kk < 16; ++kk) {
            float4 a = *(const float4*)&As[kk][tr * 4];
            float4 b = *(const float4*)&Bs[kk][tc * 4];
            acc[0][0] += a.x * b.x; acc[0][1] += a.x * b.y; acc[0][2] += a.x * b.z; acc[0][3] += a.x * b.w;
            acc[1][0] += a.y * b.x; acc[1][1] += a.y * b.y; acc[1][2] += a.y * b.z; acc[1][3] += a.y * b.w;
            acc[2][0] += a.z * b.x; acc[2][1] += a.z * b.y; acc[2][2] += a.z * b.z; acc[2][3] += a.z * b.w;
            acc[3][0] += a.w * b.x; acc[3][1] += a.w * b.y; acc[3][2] += a.w * b.z; acc[3][3] += a.w * b.w;
        }
    }
#pragma unroll
    for (int i = 0; i < 4; ++i) {
        int m = m0 + tr * 4 + i;
        if (m >= M) continue;
#pragma unroll
        for (int j = 0; j < 4; ++j) {
            int n = n0 + tc * 4 + j;
            if (n >= N) continue;
            float v = acc[i][j];
            if (bias1) v += bias1[n];
            if (bias2) v += bias2[n];
            C[(size_t)m * ldc + n] = v;
        }
    }
}

__global__ __launch_bounds__(256) void k_avg(const float* __restrict__ feat,
                                             float* __restrict__ avg)
{
    int id = blockIdx.x * 256 + threadIdx.x;
    int b = id >> 9, f = id & 511;
    const float* p = feat + (size_t)b * R_ * F_ + f;
    float s = 0.f;
#pragma unroll 7
    for (int r = 0; r < R_; ++r) s += p[r * F_];
    avg[id] = s * (1.0f / 49.0f);
}

// dst[j*64+b] = src[b*512+j]
__global__ __launch_bounds__(256) void k_tr(const float* __restrict__ src,
                                            float* __restrict__ dst)
{
    int id = blockIdx.x * 256 + threadIdx.x;
    int j = id >> 6, b = id & 63;
    dst[id] = src[(size_t)b * 512 + j];
}

// Hall_h[(b*31+t)*512 + j] = (f16) HallT[(t*512+j)*64 + b]
__global__ __launch_bounds__(256) void k_trHh(const float* __restrict__ HallT,
                                              _Float16* __restrict__ Hh)
{
    int id = blockIdx.x * 256 + threadIdx.x;     // 0 .. 1984*512-1
    int j = id & 511, m = id >> 9;
    int b = m / 31, t = m - b * 31;
    Hh[id] = (_Float16)HallT[((size_t)t * 512 + j) * 64 + b];
}

// fp32 -> fp16, 8 elems/thread
__global__ __launch_bounds__(256) void k_cvt(const float* __restrict__ src,
                                             _Float16* __restrict__ dst, int n)
{
    int base = (blockIdx.x * 256 + threadIdx.x) * 8;
    if (base >= n) return;
    float4 a = *(const float4*)(src + base);
    float4 b = *(const float4*)(src + base + 4);
    half8 o = { (_Float16)a.x, (_Float16)a.y, (_Float16)a.z, (_Float16)a.w,
                (_Float16)b.x, (_Float16)b.y, (_Float16)b.z, (_Float16)b.w };
    *(half8*)(dst + base) = o;
}

// ---------------------------------------------------------------------------
// MFMA fp16 NT GEMM: C[m,n] = sum_k A[m,k]*B[n,k] + bias[n]
// A [M,512] f16, B [N,512] f16, C fp32. Tile 64x64, 4 waves, 16x16x32 MFMA.
// Frag layout (m89-verified family): A/B lane l reads 8 contiguous k from row
// (l&15), k-octet (l>>4)*8. C/D: col=lane&15, row=(lane>>4)*4+reg.
// ---------------------------------------------------------------------------
__global__ __launch_bounds__(256) void gemm_nt_f16mfma(
    const _Float16* __restrict__ A, const _Float16* __restrict__ B,
    const float* __restrict__ bias, float* __restrict__ C, int M, int N)
{
    __shared__ __align__(16) _Float16 As[64][40];
    __shared__ __align__(16) _Float16 Bs[64][40];
    const int tid = threadIdx.x;
    const int w = tid >> 6, lane = tid & 63;
    const int m0 = blockIdx.y * 64, n0 = blockIdx.x * 64;
    const int srow = tid >> 2, sko = (tid & 3) * 8;
    const int fr = lane & 15, oct = lane >> 4;

    f32x4 acc[4];
#pragma unroll
    for (int nt = 0; nt < 4; ++nt) acc[nt] = (f32x4){0.f, 0.f, 0.f, 0.f};

    const bool bok = (n0 + srow) < N;
    const _Float16* ap = A + (size_t)(m0 + srow) * 512 + sko;
    const _Float16* bp = B + (size_t)(n0 + srow) * 512 + sko;

    for (int k0 = 0; k0 < 512; k0 += 32) {
        half8 av = *(const half8*)(ap + k0);
        half8 bv = {0, 0, 0, 0, 0, 0, 0, 0};
        if (bok) bv = *(const half8*)(bp + k0);
        __syncthreads();
        *(half8*)&As[srow][sko] = av;
        *(half8*)&Bs[srow][sko] = bv;
        __syncthreads();
        half8 af = *(const half8*)&As[w * 16 + fr][oct * 8];
#pragma unroll
        for (int nt = 0; nt < 4; ++nt) {
            half8 bf = *(const half8*)&Bs[nt * 16 + fr][oct * 8];
            acc[nt] = __builtin_amdgcn_mfma_f32_16x16x32_f16(af, bf, acc[nt], 0, 0, 0);
        }
    }
#pragma unroll
    for (int nt = 0; nt < 4; ++nt) {
        int nn = n0 + nt * 16 + fr;
        if (nn >= N) continue;
        float bb = bias[nn];
#pragma unroll
        for (int r = 0; r < 4; ++r) {
            int mm = m0 + w * 16 + oct * 4 + r;
            C[(size_t)mm * N + nn] = acc[nt][r] + bb;
        }
    }
}

// ---------------------------------------------------------------------------
// kStepA fused: blocks 0..63  -> dec_att (own W_dec pass) + e/softmax/ctx for b
//               blocks 64..255 -> W_hh gate partials (contiguous row panels)
// ---------------------------------------------------------------------------
__global__ __launch_bounds__(256) void kStepA(
    const float* __restrict__ hT, const float* __restrict__ W_dec,
    const float* __restrict__ b_dec, const float* __restrict__ encat,
    const float* __restrict__ feat, const float* __restrict__ v_w,
    const float* __restrict__ v_b, const float* __restrict__ W_hh,
    float* __restrict__ ctx, float* __restrict__ gH)
{
    __shared__ __align__(16) float h_s[512];
    __shared__ float da_s[512];
    __shared__ float e_s[52];
    __shared__ float al_s[52];
    __shared__ float wpan[11 * 512];
    __shared__ float red2[4][11 * 64];

    const int tid = threadIdx.x, bid = blockIdx.x;
    const int lane = tid & 63, w = tid >> 6;

    if (bid < 64) {
        const int b = bid;
        // h[b] column (strided, small)
        h_s[tid]       = hT[(size_t)tid * 64 + b];
        h_s[tid + 256] = hT[(size_t)(tid + 256) * 64 + b];
        __syncthreads();
        // dec_att: wave w rows [w*128, w*128+128), 16 rows/pass, 4 lanes/row,
        // k-interleaved (k4 = kq + 4i) -> conflict-free LDS + full-line W reads
        const int rl = lane >> 2, kq = lane & 3;
        for (int pass = 0; pass < 8; ++pass) {
            int row = w * 128 + pass * 16 + rl;
            const float* wrow = W_dec + (size_t)row * 512;
            float a0 = 0.f, a1 = 0.f;
#pragma unroll
            for (int i = 0; i < 32; i += 2) {
                int ka = kq + 4 * i, kb = kq + 4 * (i + 1);
                float4 q0 = *(const float4*)(wrow + 4 * ka);
                float4 q1 = *(const float4*)(wrow + 4 * kb);
                float4 x0 = *(const float4*)(h_s + 4 * ka);
                float4 x1 = *(const float4*)(h_s + 4 * kb);
                a0 += q0.x * x0.x + q0.y * x0.y + q0.z * x0.z + q0.w * x0.w;
                a1 += q1.x * x1.x + q1.y * x1.y + q1.z * x1.z + q1.w * x1.w;
            }
            float acc = a0 + a1;
            acc += __shfl_xor(acc, 1, 64);
            acc += __shfl_xor(acc, 2, 64);
            if (kq == 0) da_s[row] = acc + b_dec[row];
        }
        __syncthreads();
        // e[r]
        for (int r = w; r < R_; r += 4) {
            const float* er = encat + ((size_t)b * R_ + r) * 512;
            float s = 0.f;
#pragma unroll
            for (int i = 0; i < 8; ++i) {
                int j = i * 64 + lane;
                s += ftanh(er[j] + da_s[j]) * v_w[j];
            }
#pragma unroll
            for (int off = 32; off; off >>= 1) s += __shfl_down(s, off, 64);
            if (lane == 0) e_s[r] = s + v_b[0];
        }
        __syncthreads();
        if (tid < 64) {
            float x = (lane < R_) ? e_s[lane] : -1e30f;
            float mx = x;
#pragma unroll
            for (int off = 32; off; off >>= 1) mx = fmaxf(mx, __shfl_xor(mx, off, 64));
            float ex = (lane < R_) ? __expf(x - mx) : 0.f;
            float sm = ex;
#pragma unroll
            for (int off = 32; off; off >>= 1) sm += __shfl_xor(sm, off, 64);
            if (lane < R_) al_s[lane] = ex / sm;
        }
        __syncthreads();
#pragma unroll
        for (int p = 0; p < 2; ++p) {
            int f = tid + p * 256;
            const float* fp = feat + (size_t)b * R_ * F_ + f;
            float s = 0.f;
            for (int r = 0; r < R_; ++r) s += al_s[r] * fp[(size_t)r * 512];
            ctx[(size_t)b * 512 + f] = s;
        }
    } else {
        const int jb = bid - 64;
        const int n     = (jb < 128) ? 11 : 10;
        const int start = (jb < 128) ? jb * 11 : 1408 + (jb - 128) * 10;
        for (int idx = tid * 4; idx < n * 512; idx += 1024)
            *(float4*)&wpan[idx] = *(const float4*)&W_hh[(size_t)start * 512 + idx];
        __syncthreads();
        float acc[11] = {};
        for (int j4 = 32 * w; j4 < 32 * w + 32; ++j4) {
            int j = j4 * 4;
            float x0 = hT[(j + 0) * 64 + lane];
            float x1 = hT[(j + 1) * 64 + lane];
            float x2 = hT[(j + 2) * 64 + lane];
            float x3 = hT[(j + 3) * 64 + lane];
#pragma unroll
            for (int r = 0; r < 11; ++r) {
                float4 wv = *(const float4*)&wpan[r * 512 + j];
                acc[r] += wv.x * x0 + wv.y * x1 + wv.z * x2 + wv.w * x3;
            }
        }
#pragma unroll
        for (int r = 0; r < 11; ++r) red2[w][r * 64 + lane] = acc[r];
        __syncthreads();
        for (int o = tid; o < n * 64; o += 256) {
            float s = red2[0][o] + red2[1][o] + red2[2][o] + red2[3][o];
            gH[(size_t)(start + (o >> 6)) * 64 + (o & 63)] = s;
        }
    }
}

// ---------------------------------------------------------------------------
// kStepB: gates = (W_ih[:,512:]*ctx from LDS) + gH + embg; LSTM pointwise.
// ---------------------------------------------------------------------------
__global__ __launch_bounds__(256) void kStepB(
    const float* __restrict__ ctx, const float* __restrict__ gH,
    const float* __restrict__ embg, const float* __restrict__ W_ih,
    float* __restrict__ cT, float* __restrict__ hTn,
    float* __restrict__ HallT, int t)
{
    __shared__ __align__(16) float xls[64 * 524];   // 134 KB
    __shared__ __align__(16) float wp[8 * 512];     // 16 KB; later red + gsm
    const int tid = threadIdx.x, bid = blockIdx.x;
    const int lane = tid & 63, w = tid >> 6;
    const int j0 = 2 * bid;

    for (int idx = tid * 4; idx < 64 * 512; idx += 1024) {
        int b = idx >> 9, k = idx & 511;
        *(float4*)&xls[b * 524 + k] = *(const float4*)&ctx[(size_t)b * 512 + k];
    }
    for (int idx = tid * 4; idx < 8 * 512; idx += 1024) {
        int rr = idx >> 9, k = idx & 511;
        int row = (rr >> 1) * 512 + j0 + (rr & 1);
        *(float4*)&wp[idx] = *(const float4*)&W_ih[(size_t)row * 1024 + 512 + k];
    }
    __syncthreads();
    float acc[8] = {};
    const float* xrow = &xls[lane * 524];
    for (int j4 = 32 * w; j4 < 32 * w + 32; ++j4) {
        float4 x = *(const float4*)&xrow[j4 * 4];
#pragma unroll
        for (int r = 0; r < 8; ++r) {
            float4 wv = *(const float4*)&wp[r * 512 + j4 * 4];
            acc[r] += wv.x * x.x + wv.y * x.y + wv.z * x.z + wv.w * x.w;
        }
    }
    __syncthreads();
    float* red = wp;                 // [4][512]
#pragma unroll
    for (int r = 0; r < 8; ++r) red[w * 512 + r * 64 + lane] = acc[r];
    __syncthreads();
    float* gsm = wp + 2048;          // [8][64]
    for (int o = tid; o < 512; o += 256) {
        int rr = o >> 6, b = o & 63;
        int row = (rr >> 1) * 512 + j0 + (rr & 1);
        float s = red[o] + red[512 + o] + red[1024 + o] + red[1536 + o]
                + gH[(size_t)row * 64 + b]
                + embg[((size_t)b * TT + t) * 2048 + row];
        gsm[o] = s;
    }
    __syncthreads();
    if (tid < 128) {
        int jr = tid >> 6, b = tid & 63;
        int j = j0 + jr;
        float ig = fsigm(gsm[(0 * 2 + jr) * 64 + b]);
        float fg = fsigm(gsm[(1 * 2 + jr) * 64 + b]);
        float gg = ftanh(gsm[(2 * 2 + jr) * 64 + b]);
        float og = fsigm(gsm[(3 * 2 + jr) * 64 + b]);
        float c  = cT[(size_t)j * 64 + b];
        float cn = fg * c + ig * gg;
        float hn = og * ftanh(cn);
        cT[(size_t)j * 64 + b]  = cn;
        hTn[(size_t)j * 64 + b] = hn;
        HallT[((size_t)t * 512 + j) * 64 + b] = hn;
    }
}

// ---------------------------------------------------------------------------
extern "C" void kernel_launch(void* const* d_in, const int* in_sizes, int n_in,
                              void* d_out, int out_size, void* d_ws, size_t ws_size,
                              hipStream_t stream)
{
    (void)in_sizes; (void)n_in; (void)out_size; (void)ws_size;
    const float* feat     = (const float*)d_in[0];
    const float* caps     = (const float*)d_in[1];
    const float* W_enc    = (const float*)d_in[2];
    const float* b_enc    = (const float*)d_in[3];
    const float* W_dec    = (const float*)d_in[4];
    const float* b_dec    = (const float*)d_in[5];
    const float* v_w      = (const float*)d_in[6];
    const float* v_b      = (const float*)d_in[7];
    const float* W_ih     = (const float*)d_in[8];
    const float* W_hh     = (const float*)d_in[9];
    const float* b_ih     = (const float*)d_in[10];
    const float* b_hh     = (const float*)d_in[11];
    const float* W_init_h = (const float*)d_in[12];
    const float* b_init_h = (const float*)d_in[13];
    const float* W_init_c = (const float*)d_in[14];
    const float* b_init_c = (const float*)d_in[15];
    const float* W_out    = (const float*)d_in[16];
    const float* b_out    = (const float*)d_in[17];
    float* out = (float*)d_out;
    float* ws  = (float*)d_ws;

    // workspace (floats), ~28.4 MB (unchanged footprint)
    float* hT    = ws;                                   // 2 * 32768 ping-pong [j][b]
    float* cT    = ws + 65536;                           // 32768 [j][b]
    float* ctx   = ws + 98304;                           // 32768 [b][k]   (pre: avg)
    float* gH    = ws + 131072;                          // 131072 [row][b](pre: h0tmp,c0tmp)
    float* encat = ws + 262144;                          // 1,605,632
    float* embg  = encat + (size_t)B_ * R_ * H_;         // 4,194,304
    float* HallT = embg + (size_t)B_ * TT * 2048;        // 1,015,808

    float* avg   = ctx;          // dead before kStepA writes ctx
    float* h0tmp = gH;           // dead before kStepA writes gH
    float* c0tmp = gH + 32768;   // ditto
    // fp16 buffers alias dead embg after decode:
    _Float16* Hh = (_Float16*)embg;                      // 1984*512 f16 (2 MB)
    _Float16* Wh = (_Float16*)(embg + 600000);           // 10000*512 f16 (10.24 MB)

    dim3 thr(256);

    k_avg<<<128, thr, 0, stream>>>(feat, avg);
    gemm_nt_f32<<<dim3(8, 1), thr, 0, stream>>>(avg, 512, W_init_h, 512, b_init_h, nullptr,
                                                h0tmp, 512, 64, 512, 512);
    gemm_nt_f32<<<dim3(8, 1), thr, 0, stream>>>(avg, 512, W_init_c, 512, b_init_c, nullptr,
                                                c0tmp, 512, 64, 512, 512);
    gemm_nt_f32<<<dim3(8, 49), thr, 0, stream>>>(feat, 512, W_enc, 512, b_enc, nullptr,
                                                 encat, 512, 3136, 512, 512);
    gemm_nt_f32<<<dim3(32, 32), thr, 0, stream>>>(caps, 512, W_ih, 1024, b_ih, b_hh,
                                                  embg, 2048, 2048, 2048, 512);
    k_tr<<<128, thr, 0, stream>>>(h0tmp, hT);    // h0 -> hT buffer 0
    k_tr<<<128, thr, 0, stream>>>(c0tmp, cT);    // c0 -> cT

    for (int t = 0; t < TS; ++t) {
        const float* hR = hT + (size_t)(t & 1) * (H_ * 64);
        float*       hN = hT + (size_t)((t + 1) & 1) * (H_ * 64);
        kStepA<<<256, thr, 0, stream>>>(hR, W_dec, b_dec, encat, feat, v_w, v_b,
                                        W_hh, ctx, gH);
        kStepB<<<256, thr, 0, stream>>>(ctx, gH, embg, W_ih, cT, hN, HallT, t);
    }

    // fp16 logits path: Hall transpose+cvt, W_out cvt, MFMA GEMM
    k_trHh<<<3968, thr, 0, stream>>>(HallT, Hh);
    k_cvt<<<2500, thr, 0, stream>>>(W_out, Wh, V_ * 512);
    gemm_nt_f16mfma<<<dim3(157, 31), thr, 0, stream>>>(Hh, Wh, b_out, out, 1984, V_);
}

// Round 7
// 1300.892 us; speedup vs baseline: 1.9507x; 1.9507x over previous
//
#include <hip/hip_runtime.h>
#include <cstddef>

// Problem dims
#define B_  64
#define R_  49
#define F_  512
#define H_  512
#define V_  10000
#define TT  32
#define TS  31

typedef _Float16 half8 __attribute__((ext_vector_type(8)));
typedef float    f32x4 __attribute__((ext_vector_type(4)));

__device__ __forceinline__ float fsigm(float x) { return 1.0f / (1.0f + __expf(-x)); }
__device__ __forceinline__ float ftanh(float x) { return 1.0f - 2.0f / (__expf(2.0f * x) + 1.0f); }

// ---------------------------------------------------------------------------
// Generic fp32 NT GEMM (pre-phase only)
// ---------------------------------------------------------------------------
__global__ __launch_bounds__(256) void gemm_nt_f32(
    const float* __restrict__ A, int lda,
    const float* __restrict__ Bm, int ldb,
    const float* __restrict__ bias1, const float* __restrict__ bias2,
    float* __restrict__ C, int ldc, int M, int N, int K)
{
    __shared__ __align__(16) float As[16][68];
    __shared__ __align__(16) float Bs[16][68];
    const int tid = threadIdx.x;
    const int m0 = blockIdx.y * 64, n0 = blockIdx.x * 64;
    const int tr = tid >> 4, tc = tid & 15;
    const int lrow = tid >> 2, lk4 = (tid & 3) * 4;
    const bool am = (m0 + lrow) < M;
    const bool bn = (n0 + lrow) < N;
    const float* aptr = A + (size_t)(m0 + lrow) * lda + lk4;
    const float* bptr = Bm + (size_t)(n0 + lrow) * ldb + lk4;
    float acc[4][4] = {};

    for (int k0 = 0; k0 < K; k0 += 16) {
        float4 av = make_float4(0.f, 0.f, 0.f, 0.f);
        float4 bv = make_float4(0.f, 0.f, 0.f, 0.f);
        if (am) av = *(const float4*)(aptr + k0);
        if (bn) bv = *(const float4*)(bptr + k0);
        __syncthreads();
        As[lk4 + 0][lrow] = av.x; As[lk4 + 1][lrow] = av.y;
        As[lk4 + 2][lrow] = av.z; As[lk4 + 3][lrow] = av.w;
        Bs[lk4 + 0][lrow] = bv.x; Bs[lk4 + 1][lrow] = bv.y;
        Bs[lk4 + 2][lrow] = bv.z; Bs[lk4 + 3][lrow] = bv.w;
        __syncthreads();
#pragma unroll
        for (int kk = 0; kk < 16; ++kk) {
            float4 a = *(const float4*)&As[kk][tr * 4];
            float4 b = *(const float4*)&Bs[kk][tc * 4];
            acc[0][0] += a.x * b.x; acc[0][1] += a.x * b.y; acc[0][2] += a.x * b.z; acc[0][3] += a.x * b.w;
            acc[1][0] += a.y * b.x; acc[1][1] += a.y * b.y; acc[1][2] += a.y * b.z; acc[1][3] += a.y * b.w;
            acc[2][0] += a.z * b.x; acc[2][1] += a.z * b.y; acc[2][2] += a.z * b.z; acc[2][3] += a.z * b.w;
            acc[3][0] += a.w * b.x; acc[3][1] += a.w * b.y; acc[3][2] += a.w * b.z; acc[3][3] += a.w * b.w;
        }
    }
#pragma unroll
    for (int i = 0; i < 4; ++i) {
        int m = m0 + tr * 4 + i;
        if (m >= M) continue;
#pragma unroll
        for (int j = 0; j < 4; ++j) {
            int n = n0 + tc * 4 + j;
            if (n >= N) continue;
            float v = acc[i][j];
            if (bias1) v += bias1[n];
            if (bias2) v += bias2[n];
            C[(size_t)m * ldc + n] = v;
        }
    }
}

__global__ __launch_bounds__(256) void k_avg(const float* __restrict__ feat,
                                             float* __restrict__ avg)
{
    int id = blockIdx.x * 256 + threadIdx.x;
    int b = id >> 9, f = id & 511;
    const float* p = feat + (size_t)b * R_ * F_ + f;
    float s = 0.f;
#pragma unroll 7
    for (int r = 0; r < R_; ++r) s += p[r * F_];
    avg[id] = s * (1.0f / 49.0f);
}

// dst[j*64+b] = src[b*512+j]
__global__ __launch_bounds__(256) void k_tr(const float* __restrict__ src,
                                            float* __restrict__ dst)
{
    int id = blockIdx.x * 256 + threadIdx.x;
    int j = id >> 6, b = id & 63;
    dst[id] = src[(size_t)b * 512 + j];
}

// Hh[(b*31+t)*512 + j] = (f16) HallT[(t*512+j)*64 + b]
__global__ __launch_bounds__(256) void k_trHh(const float* __restrict__ HallT,
                                              _Float16* __restrict__ Hh)
{
    int id = blockIdx.x * 256 + threadIdx.x;     // 0 .. 1984*512-1
    int j = id & 511, m = id >> 9;
    int b = m / 31, t = m - b * 31;
    Hh[id] = (_Float16)HallT[((size_t)t * 512 + j) * 64 + b];
}

// fp32 -> fp16, 8 elems/thread
__global__ __launch_bounds__(256) void k_cvt(const float* __restrict__ src,
                                             _Float16* __restrict__ dst, int n)
{
    int base = (blockIdx.x * 256 + threadIdx.x) * 8;
    if (base >= n) return;
    float4 a = *(const float4*)(src + base);
    float4 b = *(const float4*)(src + base + 4);
    half8 o = { (_Float16)a.x, (_Float16)a.y, (_Float16)a.z, (_Float16)a.w,
                (_Float16)b.x, (_Float16)b.y, (_Float16)b.z, (_Float16)b.w };
    *(half8*)(dst + base) = o;
}

// ---------------------------------------------------------------------------
// MFMA fp16 NT GEMM: C[m,n] = sum_k A[m,k]*B[n,k] + bias[n]
// A [M,512] f16, B [N,512] f16, C fp32. Tile 64x64, 4 waves, 16x16x32 MFMA.
// ---------------------------------------------------------------------------
__global__ __launch_bounds__(256) void gemm_nt_f16mfma(
    const _Float16* __restrict__ A, const _Float16* __restrict__ B,
    const float* __restrict__ bias, float* __restrict__ C, int M, int N)
{
    __shared__ __align__(16) _Float16 As[64][40];
    __shared__ __align__(16) _Float16 Bs[64][40];
    const int tid = threadIdx.x;
    const int w = tid >> 6, lane = tid & 63;
    const int m0 = blockIdx.y * 64, n0 = blockIdx.x * 64;
    const int srow = tid >> 2, sko = (tid & 3) * 8;
    const int fr = lane & 15, oct = lane >> 4;

    f32x4 acc[4];
#pragma unroll
    for (int nt = 0; nt < 4; ++nt) acc[nt] = (f32x4){0.f, 0.f, 0.f, 0.f};

    const bool bok = (n0 + srow) < N;
    const _Float16* ap = A + (size_t)(m0 + srow) * 512 + sko;
    const _Float16* bp = B + (size_t)(n0 + srow) * 512 + sko;

    for (int k0 = 0; k0 < 512; k0 += 32) {
        half8 av = *(const half8*)(ap + k0);
        half8 bv = {0, 0, 0, 0, 0, 0, 0, 0};
        if (bok) bv = *(const half8*)(bp + k0);
        __syncthreads();
        *(half8*)&As[srow][sko] = av;
        *(half8*)&Bs[srow][sko] = bv;
        __syncthreads();
        half8 af = *(const half8*)&As[w * 16 + fr][oct * 8];
#pragma unroll
        for (int nt = 0; nt < 4; ++nt) {
            half8 bf = *(const half8*)&Bs[nt * 16 + fr][oct * 8];
            acc[nt] = __builtin_amdgcn_mfma_f32_16x16x32_f16(af, bf, acc[nt], 0, 0, 0);
        }
    }
#pragma unroll
    for (int nt = 0; nt < 4; ++nt) {
        int nn = n0 + nt * 16 + fr;
        if (nn >= N) continue;
        float bb = bias[nn];
#pragma unroll
        for (int r = 0; r < 4; ++r) {
            int mm = m0 + w * 16 + oct * 4 + r;
            C[(size_t)mm * N + nn] = acc[nt][r] + bb;
        }
    }
}

// ---------------------------------------------------------------------------
// K1: dec_att. Block owns rows {2bid, 2bid+1} of W_dec. lane=b, wave=k-quarter.
// ---------------------------------------------------------------------------
__global__ __launch_bounds__(256) void kStep1(
    const float* __restrict__ hT, const float* __restrict__ W_dec,
    const float* __restrict__ b_dec, float* __restrict__ dTT)
{
    __shared__ float red[8][64];
    const int tid = threadIdx.x, bid = blockIdx.x;
    const int lane = tid & 63, w = tid >> 6;
    const int j0 = 2 * bid;
    const float* w0 = W_dec + (size_t)j0 * 512;
    const float* w1 = w0 + 512;
    float a0 = 0.f, a1 = 0.f;
#pragma unroll 8
    for (int j = 128 * w; j < 128 * w + 128; ++j) {
        float x = hT[j * 64 + lane];
        a0 += w0[j] * x;
        a1 += w1[j] * x;
    }
    red[w * 2 + 0][lane] = a0;
    red[w * 2 + 1][lane] = a1;
    __syncthreads();
    if (tid < 128) {
        int r = tid >> 6, b = tid & 63;
        float s = red[r][b] + red[2 + r][b] + red[4 + r][b] + red[6 + r][b];
        dTT[(j0 + r) * 64 + b] = s + b_dec[j0 + r];
    }
}

// ---------------------------------------------------------------------------
// K2 fused: blocks 0..63 -> e/softmax/ctx for batch b=bid.
//           blocks 64..255 -> W_hh gate partials (contiguous row panels).
// ---------------------------------------------------------------------------
__global__ __launch_bounds__(256) void kStep2(
    const float* __restrict__ hT, const float* __restrict__ dTT,
    const float* __restrict__ encat, const float* __restrict__ feat,
    const float* __restrict__ v_w, const float* __restrict__ v_b,
    const float* __restrict__ W_hh, float* __restrict__ ctx,
    float* __restrict__ gH)
{
    const int tid = threadIdx.x, bid = blockIdx.x;
    const int lane = tid & 63, w = tid >> 6;
    if (bid < 64) {
        __shared__ float da[512];
        __shared__ float esh[52];
        __shared__ float al[52];
        const int b = bid;
        da[tid]       = dTT[(size_t)tid * 64 + b];
        da[tid + 256] = dTT[(size_t)(tid + 256) * 64 + b];
        __syncthreads();
        for (int r = w; r < R_; r += 4) {
            const float* er = encat + ((size_t)b * R_ + r) * 512;
            float s = 0.f;
#pragma unroll
            for (int i = 0; i < 8; ++i) {
                int j = i * 64 + lane;
                s += ftanh(er[j] + da[j]) * v_w[j];
            }
#pragma unroll
            for (int off = 32; off; off >>= 1) s += __shfl_down(s, off, 64);
            if (lane == 0) esh[r] = s + v_b[0];
        }
        __syncthreads();
        if (tid < 64) {
            float x = (lane < R_) ? esh[lane] : -1e30f;
            float mx = x;
#pragma unroll
            for (int off = 32; off; off >>= 1) mx = fmaxf(mx, __shfl_xor(mx, off, 64));
            float ex = (lane < R_) ? __expf(x - mx) : 0.f;
            float sm = ex;
#pragma unroll
            for (int off = 32; off; off >>= 1) sm += __shfl_xor(sm, off, 64);
            if (lane < R_) al[lane] = ex / sm;
        }
        __syncthreads();
#pragma unroll
        for (int p = 0; p < 2; ++p) {
            int f = tid + p * 256;
            const float* fp = feat + (size_t)b * R_ * F_ + f;
            float s = 0.f;
            for (int r = 0; r < R_; ++r) s += al[r] * fp[(size_t)r * 512];
            ctx[(size_t)b * 512 + f] = s;
        }
    } else {
        __shared__ float wpan[11 * 512];      // contiguous W_hh row panel
        __shared__ float red2[4][11 * 64];
        const int jb = bid - 64;
        const int n     = (jb < 128) ? 11 : 10;
        const int start = (jb < 128) ? jb * 11 : 1408 + (jb - 128) * 10;
        for (int idx = tid * 4; idx < n * 512; idx += 1024)
            *(float4*)&wpan[idx] = *(const float4*)&W_hh[(size_t)start * 512 + idx];
        __syncthreads();
        float acc[11] = {};
        for (int j4 = 32 * w; j4 < 32 * w + 32; ++j4) {
            int j = j4 * 4;
            float x0 = hT[(j + 0) * 64 + lane];
            float x1 = hT[(j + 1) * 64 + lane];
            float x2 = hT[(j + 2) * 64 + lane];
            float x3 = hT[(j + 3) * 64 + lane];
#pragma unroll
            for (int r = 0; r < 11; ++r) {
                float4 wv = *(const float4*)&wpan[r * 512 + j];
                acc[r] += wv.x * x0 + wv.y * x1 + wv.z * x2 + wv.w * x3;
            }
        }
#pragma unroll
        for (int r = 0; r < 11; ++r) red2[w][r * 64 + lane] = acc[r];
        __syncthreads();
        for (int o = tid; o < n * 64; o += 256) {
            float s = red2[0][o] + red2[1][o] + red2[2][o] + red2[3][o];
            gH[(size_t)(start + (o >> 6)) * 64 + (o & 63)] = s;
        }
    }
}

// ---------------------------------------------------------------------------
// K3: gates = (W_ih[:,512:]*ctx) + gH + embg; LSTM pointwise.
// Block owns j-pair {2bid, 2bid+1} (8 gate rows). W_ih rows in LDS (broadcast
// reads); ctx read DIRECT from global (each element used once -> no staging).
// ---------------------------------------------------------------------------
__global__ __launch_bounds__(256) void kStep3(
    const float* __restrict__ ctx, const float* __restrict__ gH,
    const float* __restrict__ embg, const float* __restrict__ W_ih,
    float* __restrict__ cT, float* __restrict__ hTn,
    float* __restrict__ HallT, int t)
{
    __shared__ __align__(16) float wp[8 * 512];     // 16 KB; later red + gsm
    const int tid = threadIdx.x, bid = blockIdx.x;
    const int lane = tid & 63, w = tid >> 6;
    const int j0 = 2 * bid;

    for (int idx = tid * 4; idx < 8 * 512; idx += 1024) {
        int rr = idx >> 9, k = idx & 511;
        int row = (rr >> 1) * 512 + j0 + (rr & 1);
        *(float4*)&wp[idx] = *(const float4*)&W_ih[(size_t)row * 1024 + 512 + k];
    }
    __syncthreads();
    float acc[8] = {};
    const float* xrow = ctx + (size_t)lane * 512;   // b = lane
    for (int j4 = 32 * w; j4 < 32 * w + 32; ++j4) {
        float4 x = *(const float4*)&xrow[j4 * 4];
#pragma unroll
        for (int r = 0; r < 8; ++r) {
            float4 wv = *(const float4*)&wp[r * 512 + j4 * 4];
            acc[r] += wv.x * x.x + wv.y * x.y + wv.z * x.z + wv.w * x.w;
        }
    }
    __syncthreads();                 // wp reads done
    float* red = wp;                 // [4][512]
#pragma unroll
    for (int r = 0; r < 8; ++r) red[w * 512 + r * 64 + lane] = acc[r];
    __syncthreads();
    float* gsm = wp + 2048;          // [8][64]
    for (int o = tid; o < 512; o += 256) {
        int rr = o >> 6, b = o & 63;
        int row = (rr >> 1) * 512 + j0 + (rr & 1);
        float s = red[o] + red[512 + o] + red[1024 + o] + red[1536 + o]
                + gH[(size_t)row * 64 + b]
                + embg[((size_t)b * TT + t) * 2048 + row];
        gsm[o] = s;
    }
    __syncthreads();
    if (tid < 128) {
        int jr = tid >> 6, b = tid & 63;
        int j = j0 + jr;
        float ig = fsigm(gsm[(0 * 2 + jr) * 64 + b]);
        float fg = fsigm(gsm[(1 * 2 + jr) * 64 + b]);
        float gg = ftanh(gsm[(2 * 2 + jr) * 64 + b]);
        float og = fsigm(gsm[(3 * 2 + jr) * 64 + b]);
        float c  = cT[(size_t)j * 64 + b];
        float cn = fg * c + ig * gg;
        float hn = og * ftanh(cn);
        cT[(size_t)j * 64 + b]  = cn;
        hTn[(size_t)j * 64 + b] = hn;
        HallT[((size_t)t * 512 + j) * 64 + b] = hn;
    }
}

// ---------------------------------------------------------------------------
extern "C" void kernel_launch(void* const* d_in, const int* in_sizes, int n_in,
                              void* d_out, int out_size, void* d_ws, size_t ws_size,
                              hipStream_t stream)
{
    (void)in_sizes; (void)n_in; (void)out_size; (void)ws_size;
    const float* feat     = (const float*)d_in[0];
    const float* caps     = (const float*)d_in[1];
    const float* W_enc    = (const float*)d_in[2];
    const float* b_enc    = (const float*)d_in[3];
    const float* W_dec    = (const float*)d_in[4];
    const float* b_dec    = (const float*)d_in[5];
    const float* v_w      = (const float*)d_in[6];
    const float* v_b      = (const float*)d_in[7];
    const float* W_ih     = (const float*)d_in[8];
    const float* W_hh     = (const float*)d_in[9];
    const float* b_ih     = (const float*)d_in[10];
    const float* b_hh     = (const float*)d_in[11];
    const float* W_init_h = (const float*)d_in[12];
    const float* b_init_h = (const float*)d_in[13];
    const float* W_init_c = (const float*)d_in[14];
    const float* b_init_c = (const float*)d_in[15];
    const float* W_out    = (const float*)d_in[16];
    const float* b_out    = (const float*)d_in[17];
    float* out = (float*)d_out;
    float* ws  = (float*)d_ws;

    // workspace (floats), ~28.4 MB
    float* hT    = ws;                                   // 2 * 32768 ping-pong [j][b]
    float* cT    = ws + 65536;                           // 32768 [j][b]
    float* dTT   = ws + 98304;                           // 32768 [j][b]   (pre: avg)
    float* ctx   = ws + 131072;                          // 32768 [b][k]   (pre: h0tmp)
    float* gH    = ws + 163840;                          // 131072 [row][b](pre: c0tmp)
    float* encat = ws + 294912;                          // 1,605,632
    float* embg  = encat + (size_t)B_ * R_ * H_;         // 4,194,304
    float* HallT = embg + (size_t)B_ * TT * 2048;        // 1,015,808

    float* avg   = dTT;    // dead before kStep1 first writes dTT
    float* h0tmp = ctx;    // dead before kStep2 first writes ctx
    float* c0tmp = gH;     // dead before kStep2 first writes gH
    // fp16 buffers alias embg (dead after decode loop):
    _Float16* Hh = (_Float16*)embg;                      // 1984*512 f16
    _Float16* Wh = (_Float16*)(embg + 600000);           // 10000*512 f16

    dim3 thr(256);

    k_avg<<<128, thr, 0, stream>>>(feat, avg);
    gemm_nt_f32<<<dim3(8, 1), thr, 0, stream>>>(avg, 512, W_init_h, 512, b_init_h, nullptr,
                                                h0tmp, 512, 64, 512, 512);
    gemm_nt_f32<<<dim3(8, 1), thr, 0, stream>>>(avg, 512, W_init_c, 512, b_init_c, nullptr,
                                                c0tmp, 512, 64, 512, 512);
    gemm_nt_f32<<<dim3(8, 49), thr, 0, stream>>>(feat, 512, W_enc, 512, b_enc, nullptr,
                                                 encat, 512, 3136, 512, 512);
    gemm_nt_f32<<<dim3(32, 32), thr, 0, stream>>>(caps, 512, W_ih, 1024, b_ih, b_hh,
                                                  embg, 2048, 2048, 2048, 512);
    k_tr<<<128, thr, 0, stream>>>(h0tmp, hT);    // h0 -> hT buffer 0
    k_tr<<<128, thr, 0, stream>>>(c0tmp, cT);    // c0 -> cT

    for (int t = 0; t < TS; ++t) {
        const float* hR = hT + (size_t)(t & 1) * (H_ * 64);
        float*       hN = hT + (size_t)((t + 1) & 1) * (H_ * 64);
        kStep1<<<256, thr, 0, stream>>>(hR, W_dec, b_dec, dTT);
        kStep2<<<256, thr, 0, stream>>>(hR, dTT, encat, feat, v_w, v_b, W_hh, ctx, gH);
        kStep3<<<256, thr, 0, stream>>>(ctx, gH, embg, W_ih, cT, hN, HallT, t);
    }

    // fp16 logits path (aliases embg AFTER decode): transpose+cvt, cvt, MFMA
    k_trHh<<<3968, thr, 0, stream>>>(HallT, Hh);
    k_cvt<<<2500, thr, 0, stream>>>(W_out, Wh, V_ * 512);
    gemm_nt_f16mfma<<<dim3(157, 31), thr, 0, stream>>>(Hh, Wh, b_out, out, 1984, V_);
}

// Round 8
// 1254.078 us; speedup vs baseline: 2.0235x; 1.0373x over previous
//
#include <hip/hip_runtime.h>
#include <cstddef>

// Problem dims
#define B_  64
#define R_  49
#define F_  512
#define H_  512
#define V_  10000
#define TT  32
#define TS  31

typedef _Float16 half8 __attribute__((ext_vector_type(8)));
typedef _Float16 half4_t __attribute__((ext_vector_type(4)));
typedef float    f32x4 __attribute__((ext_vector_type(4)));

__device__ __forceinline__ float fsigm(float x) { return 1.0f / (1.0f + __expf(-x)); }
__device__ __forceinline__ float ftanh(float x) { return 1.0f - 2.0f / (__expf(2.0f * x) + 1.0f); }

// ---------------------------------------------------------------------------
// Generic fp32 NT GEMM (h0/c0 only now)
// ---------------------------------------------------------------------------
__global__ __launch_bounds__(256) void gemm_nt_f32(
    const float* __restrict__ A, int lda,
    const float* __restrict__ Bm, int ldb,
    const float* __restrict__ bias1, const float* __restrict__ bias2,
    float* __restrict__ C, int ldc, int M, int N, int K)
{
    __shared__ __align__(16) float As[16][68];
    __shared__ __align__(16) float Bs[16][68];
    const int tid = threadIdx.x;
    const int m0 = blockIdx.y * 64, n0 = blockIdx.x * 64;
    const int tr = tid >> 4, tc = tid & 15;
    const int lrow = tid >> 2, lk4 = (tid & 3) * 4;
    const bool am = (m0 + lrow) < M;
    const bool bn = (n0 + lrow) < N;
    const float* aptr = A + (size_t)(m0 + lrow) * lda + lk4;
    const float* bptr = Bm + (size_t)(n0 + lrow) * ldb + lk4;
    float acc[4][4] = {};

    for (int k0 = 0; k0 < K; k0 += 16) {
        float4 av = make_float4(0.f, 0.f, 0.f, 0.f);
        float4 bv = make_float4(0.f, 0.f, 0.f, 0.f);
        if (am) av = *(const float4*)(aptr + k0);
        if (bn) bv = *(const float4*)(bptr + k0);
        __syncthreads();
        As[lk4 + 0][lrow] = av.x; As[lk4 + 1][lrow] = av.y;
        As[lk4 + 2][lrow] = av.z; As[lk4 + 3][lrow] = av.w;
        Bs[lk4 + 0][lrow] = bv.x; Bs[lk4 + 1][lrow] = bv.y;
        Bs[lk4 + 2][lrow] = bv.z; Bs[lk4 + 3][lrow] = bv.w;
        __syncthreads();
#pragma unroll
        for (int kk = 0; kk < 16; ++kk) {
            float4 a = *(const float4*)&As[kk][tr * 4];
            float4 b = *(const float4*)&Bs[kk][tc * 4];
            acc[0][0] += a.x * b.x; acc[0][1] += a.x * b.y; acc[0][2] += a.x * b.z; acc[0][3] += a.x * b.w;
            acc[1][0] += a.y * b.x; acc[1][1] += a.y * b.y; acc[1][2] += a.y * b.z; acc[1][3] += a.y * b.w;
            acc[2][0] += a.z * b.x; acc[2][1] += a.z * b.y; acc[2][2] += a.z * b.z; acc[2][3] += a.z * b.w;
            acc[3][0] += a.w * b.x; acc[3][1] += a.w * b.y; acc[3][2] += a.w * b.z; acc[3][3] += a.w * b.w;
        }
    }
#pragma unroll
    for (int i = 0; i < 4; ++i) {
        int m = m0 + tr * 4 + i;
        if (m >= M) continue;
#pragma unroll
        for (int j = 0; j < 4; ++j) {
            int n = n0 + tc * 4 + j;
            if (n >= N) continue;
            float v = acc[i][j];
            if (bias1) v += bias1[n];
            if (bias2) v += bias2[n];
            C[(size_t)m * ldc + n] = v;
        }
    }
}

__global__ __launch_bounds__(256) void k_avg(const float* __restrict__ feat,
                                             float* __restrict__ avg)
{
    int id = blockIdx.x * 256 + threadIdx.x;
    int b = id >> 9, f = id & 511;
    const float* p = feat + (size_t)b * R_ * F_ + f;
    float s = 0.f;
#pragma unroll 7
    for (int r = 0; r < R_; ++r) s += p[r * F_];
    avg[id] = s * (1.0f / 49.0f);
}

// dst[j*64+b] = src[b*512+j]
__global__ __launch_bounds__(256) void k_tr(const float* __restrict__ src,
                                            float* __restrict__ dst)
{
    int id = blockIdx.x * 256 + threadIdx.x;
    int j = id >> 6, b = id & 63;
    dst[id] = src[(size_t)b * 512 + j];
}

// Hh[(b*31+t)*512 + j] = (f16) HallT[(t*512+j)*64 + b]
__global__ __launch_bounds__(256) void k_trHh(const float* __restrict__ HallT,
                                              _Float16* __restrict__ Hh)
{
    int id = blockIdx.x * 256 + threadIdx.x;     // 0 .. 1984*512-1
    int j = id & 511, m = id >> 9;
    int b = m / 31, t = m - b * 31;
    Hh[id] = (_Float16)HallT[((size_t)t * 512 + j) * 64 + b];
}

// fp32 -> fp16, 8 elems/thread (contiguous)
__global__ __launch_bounds__(256) void k_cvt(const float* __restrict__ src,
                                             _Float16* __restrict__ dst, int n)
{
    int base = (blockIdx.x * 256 + threadIdx.x) * 8;
    if (base >= n) return;
    float4 a = *(const float4*)(src + base);
    float4 b = *(const float4*)(src + base + 4);
    half8 o = { (_Float16)a.x, (_Float16)a.y, (_Float16)a.z, (_Float16)a.w,
                (_Float16)b.x, (_Float16)b.y, (_Float16)b.z, (_Float16)b.w };
    *(half8*)(dst + base) = o;
}

// ---------------------------------------------------------------------------
// Split-fp16 conversion: x = hi + lo, hi=(f16)x, lo=(f16)(x-hi).
// Rows of length 512 with arbitrary source row stride; dst contiguous [n][512].
// 4 elems/thread.
// ---------------------------------------------------------------------------
__global__ __launch_bounds__(256) void k_cvt_split(
    const float* __restrict__ src, int srcStride,
    _Float16* __restrict__ dstH, _Float16* __restrict__ dstL, int total4)
{
    int e4 = blockIdx.x * 256 + threadIdx.x;
    if (e4 >= total4) return;
    int row = e4 >> 7, k4 = (e4 & 127) * 4;
    float4 x = *(const float4*)(src + (size_t)row * srcStride + k4);
    half4_t h = { (_Float16)x.x, (_Float16)x.y, (_Float16)x.z, (_Float16)x.w };
    half4_t l = { (_Float16)(x.x - (float)h.x), (_Float16)(x.y - (float)h.y),
                  (_Float16)(x.z - (float)h.z), (_Float16)(x.w - (float)h.w) };
    *(half4_t*)(dstH + (size_t)row * 512 + k4) = h;
    *(half4_t*)(dstL + (size_t)row * 512 + k4) = l;
}

// ---------------------------------------------------------------------------
// Split-fp16 MFMA NT GEMM, K=512: C = A*B^T + bias1 + bias2, fp32-quality.
// acc += Ah*Bh + Ah*Bl + Al*Bh   (lo*lo dropped, ~2^-22 rel).
// Output fp32 (Cf) or fp16 (Ch) — exactly one non-null. M,N multiples of 64.
// ---------------------------------------------------------------------------
__global__ __launch_bounds__(256) void gemm_nt_f16split(
    const _Float16* __restrict__ Ah, const _Float16* __restrict__ Al,
    const _Float16* __restrict__ Bh, const _Float16* __restrict__ Bl,
    const float* __restrict__ bias1, const float* __restrict__ bias2,
    float* __restrict__ Cf, _Float16* __restrict__ Ch, int N)
{
    __shared__ __align__(16) _Float16 AsH[64][40];
    __shared__ __align__(16) _Float16 AsL[64][40];
    __shared__ __align__(16) _Float16 BsH[64][40];
    __shared__ __align__(16) _Float16 BsL[64][40];
    const int tid = threadIdx.x;
    const int w = tid >> 6, lane = tid & 63;
    const int m0 = blockIdx.y * 64, n0 = blockIdx.x * 64;
    const int srow = tid >> 2, sko = (tid & 3) * 8;
    const int fr = lane & 15, oct = lane >> 4;

    f32x4 acc[4];
#pragma unroll
    for (int nt = 0; nt < 4; ++nt) acc[nt] = (f32x4){0.f, 0.f, 0.f, 0.f};

    const _Float16* ahp = Ah + (size_t)(m0 + srow) * 512 + sko;
    const _Float16* alp = Al + (size_t)(m0 + srow) * 512 + sko;
    const _Float16* bhp = Bh + (size_t)(n0 + srow) * 512 + sko;
    const _Float16* blp = Bl + (size_t)(n0 + srow) * 512 + sko;

    for (int k0 = 0; k0 < 512; k0 += 32) {
        half8 avh = *(const half8*)(ahp + k0);
        half8 avl = *(const half8*)(alp + k0);
        half8 bvh = *(const half8*)(bhp + k0);
        half8 bvl = *(const half8*)(blp + k0);
        __syncthreads();
        *(half8*)&AsH[srow][sko] = avh;
        *(half8*)&AsL[srow][sko] = avl;
        *(half8*)&BsH[srow][sko] = bvh;
        *(half8*)&BsL[srow][sko] = bvl;
        __syncthreads();
        half8 afh = *(const half8*)&AsH[w * 16 + fr][oct * 8];
        half8 afl = *(const half8*)&AsL[w * 16 + fr][oct * 8];
#pragma unroll
        for (int nt = 0; nt < 4; ++nt) {
            half8 bfh = *(const half8*)&BsH[nt * 16 + fr][oct * 8];
            half8 bfl = *(const half8*)&BsL[nt * 16 + fr][oct * 8];
            acc[nt] = __builtin_amdgcn_mfma_f32_16x16x32_f16(afh, bfh, acc[nt], 0, 0, 0);
            acc[nt] = __builtin_amdgcn_mfma_f32_16x16x32_f16(afh, bfl, acc[nt], 0, 0, 0);
            acc[nt] = __builtin_amdgcn_mfma_f32_16x16x32_f16(afl, bfh, acc[nt], 0, 0, 0);
        }
    }
#pragma unroll
    for (int nt = 0; nt < 4; ++nt) {
        int nn = n0 + nt * 16 + fr;
        float bb = bias1 ? bias1[nn] : 0.f;
        if (bias2) bb += bias2[nn];
#pragma unroll
        for (int r = 0; r < 4; ++r) {
            int mm = m0 + w * 16 + oct * 4 + r;
            float v = acc[nt][r] + bb;
            if (Cf) Cf[(size_t)mm * N + nn] = v;
            else    Ch[(size_t)mm * N + nn] = (_Float16)v;
        }
    }
}

// ---------------------------------------------------------------------------
// MFMA fp16 NT GEMM (logits): C[m,n] = sum_k A[m,k]*B[n,k] + bias[n]
// ---------------------------------------------------------------------------
__global__ __launch_bounds__(256) void gemm_nt_f16mfma(
    const _Float16* __restrict__ A, const _Float16* __restrict__ B,
    const float* __restrict__ bias, float* __restrict__ C, int M, int N)
{
    __shared__ __align__(16) _Float16 As[64][40];
    __shared__ __align__(16) _Float16 Bs[64][40];
    const int tid = threadIdx.x;
    const int w = tid >> 6, lane = tid & 63;
    const int m0 = blockIdx.y * 64, n0 = blockIdx.x * 64;
    const int srow = tid >> 2, sko = (tid & 3) * 8;
    const int fr = lane & 15, oct = lane >> 4;

    f32x4 acc[4];
#pragma unroll
    for (int nt = 0; nt < 4; ++nt) acc[nt] = (f32x4){0.f, 0.f, 0.f, 0.f};

    const bool bok = (n0 + srow) < N;
    const _Float16* ap = A + (size_t)(m0 + srow) * 512 + sko;
    const _Float16* bp = B + (size_t)(n0 + srow) * 512 + sko;

    for (int k0 = 0; k0 < 512; k0 += 32) {
        half8 av = *(const half8*)(ap + k0);
        half8 bv = {0, 0, 0, 0, 0, 0, 0, 0};
        if (bok) bv = *(const half8*)(bp + k0);
        __syncthreads();
        *(half8*)&As[srow][sko] = av;
        *(half8*)&Bs[srow][sko] = bv;
        __syncthreads();
        half8 af = *(const half8*)&As[w * 16 + fr][oct * 8];
#pragma unroll
        for (int nt = 0; nt < 4; ++nt) {
            half8 bf = *(const half8*)&Bs[nt * 16 + fr][oct * 8];
            acc[nt] = __builtin_amdgcn_mfma_f32_16x16x32_f16(af, bf, acc[nt], 0, 0, 0);
        }
    }
#pragma unroll
    for (int nt = 0; nt < 4; ++nt) {
        int nn = n0 + nt * 16 + fr;
        if (nn >= N) continue;
        float bb = bias[nn];
#pragma unroll
        for (int r = 0; r < 4; ++r) {
            int mm = m0 + w * 16 + oct * 4 + r;
            C[(size_t)mm * N + nn] = acc[nt][r] + bb;
        }
    }
}

// ---------------------------------------------------------------------------
// K1: dec_att. Block owns rows {2bid, 2bid+1} of W_dec. lane=b, wave=k-quarter.
// ---------------------------------------------------------------------------
__global__ __launch_bounds__(256) void kStep1(
    const float* __restrict__ hT, const float* __restrict__ W_dec,
    const float* __restrict__ b_dec, float* __restrict__ dTT)
{
    __shared__ float red[8][64];
    const int tid = threadIdx.x, bid = blockIdx.x;
    const int lane = tid & 63, w = tid >> 6;
    const int j0 = 2 * bid;
    const float* w0 = W_dec + (size_t)j0 * 512;
    const float* w1 = w0 + 512;
    float a0 = 0.f, a1 = 0.f;
#pragma unroll 8
    for (int j = 128 * w; j < 128 * w + 128; ++j) {
        float x = hT[j * 64 + lane];
        a0 += w0[j] * x;
        a1 += w1[j] * x;
    }
    red[w * 2 + 0][lane] = a0;
    red[w * 2 + 1][lane] = a1;
    __syncthreads();
    if (tid < 128) {
        int r = tid >> 6, b = tid & 63;
        float s = red[r][b] + red[2 + r][b] + red[4 + r][b] + red[6 + r][b];
        dTT[(j0 + r) * 64 + b] = s + b_dec[j0 + r];
    }
}

// ---------------------------------------------------------------------------
// K2 fused: blocks 0..63 -> e/softmax/ctx for batch b=bid.
//           blocks 64..255 -> W_hh gate partials (contiguous row panels).
// ---------------------------------------------------------------------------
__global__ __launch_bounds__(256) void kStep2(
    const float* __restrict__ hT, const float* __restrict__ dTT,
    const float* __restrict__ encat, const float* __restrict__ feat,
    const float* __restrict__ v_w, const float* __restrict__ v_b,
    const float* __restrict__ W_hh, float* __restrict__ ctx,
    float* __restrict__ gH)
{
    const int tid = threadIdx.x, bid = blockIdx.x;
    const int lane = tid & 63, w = tid >> 6;
    if (bid < 64) {
        __shared__ float da[512];
        __shared__ float esh[52];
        __shared__ float al[52];
        const int b = bid;
        da[tid]       = dTT[(size_t)tid * 64 + b];
        da[tid + 256] = dTT[(size_t)(tid + 256) * 64 + b];
        __syncthreads();
        for (int r = w; r < R_; r += 4) {
            const float* er = encat + ((size_t)b * R_ + r) * 512;
            float s = 0.f;
#pragma unroll
            for (int i = 0; i < 8; ++i) {
                int j = i * 64 + lane;
                s += ftanh(er[j] + da[j]) * v_w[j];
            }
#pragma unroll
            for (int off = 32; off; off >>= 1) s += __shfl_down(s, off, 64);
            if (lane == 0) esh[r] = s + v_b[0];
        }
        __syncthreads();
        if (tid < 64) {
            float x = (lane < R_) ? esh[lane] : -1e30f;
            float mx = x;
#pragma unroll
            for (int off = 32; off; off >>= 1) mx = fmaxf(mx, __shfl_xor(mx, off, 64));
            float ex = (lane < R_) ? __expf(x - mx) : 0.f;
            float sm = ex;
#pragma unroll
            for (int off = 32; off; off >>= 1) sm += __shfl_xor(sm, off, 64);
            if (lane < R_) al[lane] = ex / sm;
        }
        __syncthreads();
#pragma unroll
        for (int p = 0; p < 2; ++p) {
            int f = tid + p * 256;
            const float* fp = feat + (size_t)b * R_ * F_ + f;
            float s = 0.f;
            for (int r = 0; r < R_; ++r) s += al[r] * fp[(size_t)r * 512];
            ctx[(size_t)b * 512 + f] = s;
        }
    } else {
        __shared__ float wpan[11 * 512];      // contiguous W_hh row panel
        __shared__ float red2[4][11 * 64];
        const int jb = bid - 64;
        const int n     = (jb < 128) ? 11 : 10;
        const int start = (jb < 128) ? jb * 11 : 1408 + (jb - 128) * 10;
        for (int idx = tid * 4; idx < n * 512; idx += 1024)
            *(float4*)&wpan[idx] = *(const float4*)&W_hh[(size_t)start * 512 + idx];
        __syncthreads();
        float acc[11] = {};
        for (int j4 = 32 * w; j4 < 32 * w + 32; ++j4) {
            int j = j4 * 4;
            float x0 = hT[(j + 0) * 64 + lane];
            float x1 = hT[(j + 1) * 64 + lane];
            float x2 = hT[(j + 2) * 64 + lane];
            float x3 = hT[(j + 3) * 64 + lane];
#pragma unroll
            for (int r = 0; r < 11; ++r) {
                float4 wv = *(const float4*)&wpan[r * 512 + j];
                acc[r] += wv.x * x0 + wv.y * x1 + wv.z * x2 + wv.w * x3;
            }
        }
#pragma unroll
        for (int r = 0; r < 11; ++r) red2[w][r * 64 + lane] = acc[r];
        __syncthreads();
        for (int o = tid; o < n * 64; o += 256) {
            float s = red2[0][o] + red2[1][o] + red2[2][o] + red2[3][o];
            gH[(size_t)(start + (o >> 6)) * 64 + (o & 63)] = s;
        }
    }
}

// ---------------------------------------------------------------------------
// K3: gates = (W_ih[:,512:]*ctx) + gH + embgH(f16); LSTM pointwise.
// ---------------------------------------------------------------------------
__global__ __launch_bounds__(256) void kStep3(
    const float* __restrict__ ctx, const float* __restrict__ gH,
    const _Float16* __restrict__ embg, const float* __restrict__ W_ih,
    float* __restrict__ cT, float* __restrict__ hTn,
    float* __restrict__ HallT, int t)
{
    __shared__ __align__(16) float wp[8 * 512];     // 16 KB; later red + gsm
    const int tid = threadIdx.x, bid = blockIdx.x;
    const int lane = tid & 63, w = tid >> 6;
    const int j0 = 2 * bid;

    for (int idx = tid * 4; idx < 8 * 512; idx += 1024) {
        int rr = idx >> 9, k = idx & 511;
        int row = (rr >> 1) * 512 + j0 + (rr & 1);
        *(float4*)&wp[idx] = *(const float4*)&W_ih[(size_t)row * 1024 + 512 + k];
    }
    __syncthreads();
    float acc[8] = {};
    const float* xrow = ctx + (size_t)lane * 512;   // b = lane
    for (int j4 = 32 * w; j4 < 32 * w + 32; ++j4) {
        float4 x = *(const float4*)&xrow[j4 * 4];
#pragma unroll
        for (int r = 0; r < 8; ++r) {
            float4 wv = *(const float4*)&wp[r * 512 + j4 * 4];
            acc[r] += wv.x * x.x + wv.y * x.y + wv.z * x.z + wv.w * x.w;
        }
    }
    __syncthreads();                 // wp reads done
    float* red = wp;                 // [4][512]
#pragma unroll
    for (int r = 0; r < 8; ++r) red[w * 512 + r * 64 + lane] = acc[r];
    __syncthreads();
    float* gsm = wp + 2048;          // [8][64]
    for (int o = tid; o < 512; o += 256) {
        int rr = o >> 6, b = o & 63;
        int row = (rr >> 1) * 512 + j0 + (rr & 1);
        float s = red[o] + red[512 + o] + red[1024 + o] + red[1536 + o]
                + gH[(size_t)row * 64 + b]
                + (float)embg[((size_t)b * TT + t) * 2048 + row];
        gsm[o] = s;
    }
    __syncthreads();
    if (tid < 128) {
        int jr = tid >> 6, b = tid & 63;
        int j = j0 + jr;
        float ig = fsigm(gsm[(0 * 2 + jr) * 64 + b]);
        float fg = fsigm(gsm[(1 * 2 + jr) * 64 + b]);
        float gg = ftanh(gsm[(2 * 2 + jr) * 64 + b]);
        float og = fsigm(gsm[(3 * 2 + jr) * 64 + b]);
        float c  = cT[(size_t)j * 64 + b];
        float cn = fg * c + ig * gg;
        float hn = og * ftanh(cn);
        cT[(size_t)j * 64 + b]  = cn;
        hTn[(size_t)j * 64 + b] = hn;
        HallT[((size_t)t * 512 + j) * 64 + b] = hn;
    }
}

// ---------------------------------------------------------------------------
extern "C" void kernel_launch(void* const* d_in, const int* in_sizes, int n_in,
                              void* d_out, int out_size, void* d_ws, size_t ws_size,
                              hipStream_t stream)
{
    (void)in_sizes; (void)n_in; (void)out_size; (void)ws_size;
    const float* feat     = (const float*)d_in[0];
    const float* caps     = (const float*)d_in[1];
    const float* W_enc    = (const float*)d_in[2];
    const float* b_enc    = (const float*)d_in[3];
    const float* W_dec    = (const float*)d_in[4];
    const float* b_dec    = (const float*)d_in[5];
    const float* v_w      = (const float*)d_in[6];
    const float* v_b      = (const float*)d_in[7];
    const float* W_ih     = (const float*)d_in[8];
    const float* W_hh     = (const float*)d_in[9];
    const float* b_ih     = (const float*)d_in[10];
    const float* b_hh     = (const float*)d_in[11];
    const float* W_init_h = (const float*)d_in[12];
    const float* b_init_h = (const float*)d_in[13];
    const float* W_init_c = (const float*)d_in[14];
    const float* b_init_c = (const float*)d_in[15];
    const float* W_out    = (const float*)d_in[16];
    const float* b_out    = (const float*)d_in[17];
    float* out = (float*)d_out;
    float* ws  = (float*)d_ws;

    // workspace layout (float slots), total 7,110,656 fl = 28.4 MB (same as R7)
    float* hT    = ws;                                   // 65,536 ping-pong [j][b]
    float* cT    = ws + 65536;                           // 32,768 [j][b]
    float* dTT   = ws + 98304;                           // 32,768 [j][b]   (pre: avg)
    float* ctx   = ws + 131072;                          // 32,768 [b][k]   (pre: h0tmp)
    float* gH    = ws + 163840;                          // 131,072 [row][b](pre: c0tmp)
    float* encat = ws + 294912;                          // 1,605,632
    _Float16* embgH = (_Float16*)(ws + 1900544);         // 4,194,304 halves (2,097,152 fl)
    float* HallT = ws + 3997696;                         // 1,015,808
    float* Z     = ws + 5013504;                         // 2,097,152 fl conversion scratch

    float* avg   = dTT;    // dead before kStep1 first writes dTT
    float* h0tmp = ctx;    // dead before kStep2 first writes ctx
    float* c0tmp = gH;     // dead before kStep2 first writes gH
    // post-decode fp16 buffers alias encat+embgH (both dead after decode):
    _Float16* Hh = (_Float16*)encat;                     // 1984*512 halves
    _Float16* Wh = (_Float16*)(encat + 600000);          // 10000*512 halves

    dim3 thr(256);

    // ---- pre-phase ----
    k_avg<<<128, thr, 0, stream>>>(feat, avg);
    gemm_nt_f32<<<dim3(8, 1), thr, 0, stream>>>(avg, 512, W_init_h, 512, b_init_h, nullptr,
                                                h0tmp, 512, 64, 512, 512);
    gemm_nt_f32<<<dim3(8, 1), thr, 0, stream>>>(avg, 512, W_init_c, 512, b_init_c, nullptr,
                                                c0tmp, 512, 64, 512, 512);

    // encat = feat @ W_enc^T + b_enc  via split-fp16 MFMA
    _Float16* featH = (_Float16*)Z;                      // 1,605,632 halves
    _Float16* featL = featH + 1605632;
    _Float16* WencH = (_Float16*)(Z + 1605632);          // 262,144 halves
    _Float16* WencL = WencH + 262144;
    k_cvt_split<<<1568, thr, 0, stream>>>(feat, 512, featH, featL, 3136 * 128);
    k_cvt_split<<<256, thr, 0, stream>>>(W_enc, 512, WencH, WencL, 512 * 128);
    gemm_nt_f16split<<<dim3(8, 49), thr, 0, stream>>>(featH, featL, WencH, WencL,
                                                      b_enc, nullptr, encat, nullptr, 512);

    // embgH = (caps @ W_ih[:,:512]^T + b_ih + b_hh) as fp16, via split-fp16 MFMA
    _Float16* capsH = (_Float16*)Z;                      // 1,048,576 halves
    _Float16* capsL = capsH + 1048576;
    _Float16* WiheH = (_Float16*)(Z + 1048576);
    _Float16* WiheL = WiheH + 1048576;
    k_cvt_split<<<1024, thr, 0, stream>>>(caps, 512, capsH, capsL, 2048 * 128);
    k_cvt_split<<<1024, thr, 0, stream>>>(W_ih, 1024, WiheH, WiheL, 2048 * 128);
    gemm_nt_f16split<<<dim3(32, 32), thr, 0, stream>>>(capsH, capsL, WiheH, WiheL,
                                                       b_ih, b_hh, nullptr, embgH, 2048);

    k_tr<<<128, thr, 0, stream>>>(h0tmp, hT);    // h0 -> hT buffer 0
    k_tr<<<128, thr, 0, stream>>>(c0tmp, cT);    // c0 -> cT

    // ---- decode ----
    for (int t = 0; t < TS; ++t) {
        const float* hR = hT + (size_t)(t & 1) * (H_ * 64);
        float*       hN = hT + (size_t)((t + 1) & 1) * (H_ * 64);
        kStep1<<<256, thr, 0, stream>>>(hR, W_dec, b_dec, dTT);
        kStep2<<<256, thr, 0, stream>>>(hR, dTT, encat, feat, v_w, v_b, W_hh, ctx, gH);
        kStep3<<<256, thr, 0, stream>>>(ctx, gH, embgH, W_ih, cT, hN, HallT, t);
    }

    // ---- post: fp16 logits ----
    k_trHh<<<3968, thr, 0, stream>>>(HallT, Hh);
    k_cvt<<<2500, thr, 0, stream>>>(W_out, Wh, V_ * 512);
    gemm_nt_f16mfma<<<dim3(157, 31), thr, 0, stream>>>(Hh, Wh, b_out, out, 1984, V_);
}

// Round 9
// 1057.490 us; speedup vs baseline: 2.3997x; 1.1859x over previous
//
#include <hip/hip_runtime.h>
#include <cstddef>

// Problem dims
#define B_  64
#define R_  49
#define F_  512
#define H_  512
#define V_  10000
#define TT  32
#define TS  31

typedef _Float16 half8 __attribute__((ext_vector_type(8)));
typedef float    f32x4 __attribute__((ext_vector_type(4)));

__device__ __forceinline__ float fsigm(float x) { return 1.0f / (1.0f + __expf(-x)); }
__device__ __forceinline__ float ftanh(float x) { return 1.0f - 2.0f / (__expf(2.0f * x) + 1.0f); }

__device__ __forceinline__ half8 cvt8(float4 a, float4 b) {
    half8 o = { (_Float16)a.x, (_Float16)a.y, (_Float16)a.z, (_Float16)a.w,
                (_Float16)b.x, (_Float16)b.y, (_Float16)b.z, (_Float16)b.w };
    return o;
}

// ---------------------------------------------------------------------------
// Generic fp32 NT GEMM (h0/c0 only)
// ---------------------------------------------------------------------------
__global__ __launch_bounds__(256) void gemm_nt_f32(
    const float* __restrict__ A, int lda,
    const float* __restrict__ Bm, int ldb,
    const float* __restrict__ bias1, const float* __restrict__ bias2,
    float* __restrict__ C, int ldc, int M, int N, int K)
{
    __shared__ __align__(16) float As[16][68];
    __shared__ __align__(16) float Bs[16][68];
    const int tid = threadIdx.x;
    const int m0 = blockIdx.y * 64, n0 = blockIdx.x * 64;
    const int tr = tid >> 4, tc = tid & 15;
    const int lrow = tid >> 2, lk4 = (tid & 3) * 4;
    const bool am = (m0 + lrow) < M;
    const bool bn = (n0 + lrow) < N;
    const float* aptr = A + (size_t)(m0 + lrow) * lda + lk4;
    const float* bptr = Bm + (size_t)(n0 + lrow) * ldb + lk4;
    float acc[4][4] = {};

    for (int k0 = 0; k0 < K; k0 += 16) {
        float4 av = make_float4(0.f, 0.f, 0.f, 0.f);
        float4 bv = make_float4(0.f, 0.f, 0.f, 0.f);
        if (am) av = *(const float4*)(aptr + k0);
        if (bn) bv = *(const float4*)(bptr + k0);
        __syncthreads();
        As[lk4 + 0][lrow] = av.x; As[lk4 + 1][lrow] = av.y;
        As[lk4 + 2][lrow] = av.z; As[lk4 + 3][lrow] = av.w;
        Bs[lk4 + 0][lrow] = bv.x; Bs[lk4 + 1][lrow] = bv.y;
        Bs[lk4 + 2][lrow] = bv.z; Bs[lk4 + 3][lrow] = bv.w;
        __syncthreads();
#pragma unroll
        for (int kk = 0; kk < 16; ++kk) {
            float4 a = *(const float4*)&As[kk][tr * 4];
            float4 b = *(const float4*)&Bs[kk][tc * 4];
            acc[0][0] += a.x * b.x; acc[0][1] += a.x * b.y; acc[0][2] += a.x * b.z; acc[0][3] += a.x * b.w;
            acc[1][0] += a.y * b.x; acc[1][1] += a.y * b.y; acc[1][2] += a.y * b.z; acc[1][3] += a.y * b.w;
            acc[2][0] += a.z * b.x; acc[2][1] += a.z * b.y; acc[2][2] += a.z * b.z; acc[2][3] += a.z * b.w;
            acc[3][0] += a.w * b.x; acc[3][1] += a.w * b.y; acc[3][2] += a.w * b.z; acc[3][3] += a.w * b.w;
        }
    }
#pragma unroll
    for (int i = 0; i < 4; ++i) {
        int m = m0 + tr * 4 + i;
        if (m >= M) continue;
#pragma unroll
        for (int j = 0; j < 4; ++j) {
            int n = n0 + tc * 4 + j;
            if (n >= N) continue;
            float v = acc[i][j];
            if (bias1) v += bias1[n];
            if (bias2) v += bias2[n];
            C[(size_t)m * ldc + n] = v;
        }
    }
}

__global__ __launch_bounds__(256) void k_avg(const float* __restrict__ feat,
                                             float* __restrict__ avg)
{
    int id = blockIdx.x * 256 + threadIdx.x;
    int b = id >> 9, f = id & 511;
    const float* p = feat + (size_t)b * R_ * F_ + f;
    float s = 0.f;
#pragma unroll 7
    for (int r = 0; r < R_; ++r) s += p[r * F_];
    avg[id] = s * (1.0f / 49.0f);
}

// dst[j*64+b] = src[b*512+j]
__global__ __launch_bounds__(256) void k_tr(const float* __restrict__ src,
                                            float* __restrict__ dst)
{
    int id = blockIdx.x * 256 + threadIdx.x;
    int j = id >> 6, b = id & 63;
    dst[id] = src[(size_t)b * 512 + j];
}

// ---------------------------------------------------------------------------
// Mixed NT GEMM: A fp32 [M,512] (lda), B fp32 [N,512] (ldb), cvt->f16 in-kernel,
// MFMA 16x16x32, out f16 (Ch) or fp32 (Cf), + bias1 + bias2.
// M, N multiples of 64. K = 512 fixed.
// ---------------------------------------------------------------------------
__global__ __launch_bounds__(256) void gemm_nt_ff(
    const float* __restrict__ A, int lda,
    const float* __restrict__ Bm, int ldb,
    const float* __restrict__ bias1, const float* __restrict__ bias2,
    float* __restrict__ Cf, _Float16* __restrict__ Ch, int N)
{
    __shared__ __align__(16) _Float16 As[64][40];
    __shared__ __align__(16) _Float16 Bs[64][40];
    const int tid = threadIdx.x;
    const int w = tid >> 6, lane = tid & 63;
    const int m0 = blockIdx.y * 64, n0 = blockIdx.x * 64;
    const int srow = tid >> 2, sko = (tid & 3) * 8;
    const int fr = lane & 15, oct = lane >> 4;

    f32x4 acc[4];
#pragma unroll
    for (int nt = 0; nt < 4; ++nt) acc[nt] = (f32x4){0.f, 0.f, 0.f, 0.f};

    const float* ap = A + (size_t)(m0 + srow) * lda + sko;
    const float* bp = Bm + (size_t)(n0 + srow) * ldb + sko;

    for (int k0 = 0; k0 < 512; k0 += 32) {
        float4 a0 = *(const float4*)(ap + k0);
        float4 a1 = *(const float4*)(ap + k0 + 4);
        float4 b0 = *(const float4*)(bp + k0);
        float4 b1 = *(const float4*)(bp + k0 + 4);
        __syncthreads();
        *(half8*)&As[srow][sko] = cvt8(a0, a1);
        *(half8*)&Bs[srow][sko] = cvt8(b0, b1);
        __syncthreads();
        half8 af = *(const half8*)&As[w * 16 + fr][oct * 8];
#pragma unroll
        for (int nt = 0; nt < 4; ++nt) {
            half8 bf = *(const half8*)&Bs[nt * 16 + fr][oct * 8];
            acc[nt] = __builtin_amdgcn_mfma_f32_16x16x32_f16(af, bf, acc[nt], 0, 0, 0);
        }
    }
#pragma unroll
    for (int nt = 0; nt < 4; ++nt) {
        int nn = n0 + nt * 16 + fr;
        float bb = bias1 ? bias1[nn] : 0.f;
        if (bias2) bb += bias2[nn];
#pragma unroll
        for (int r = 0; r < 4; ++r) {
            int mm = m0 + w * 16 + oct * 4 + r;
            float v = acc[nt][r] + bb;
            if (Cf) Cf[(size_t)mm * N + nn] = v;
            else    Ch[(size_t)mm * N + nn] = (_Float16)v;
        }
    }
}

// ---------------------------------------------------------------------------
// Logits GEMM: A f16 [M,512], B fp32 [N,512] cvt-in-kernel, out fp32 + bias.
// M multiple of 64; N bounds-checked.
// ---------------------------------------------------------------------------
__global__ __launch_bounds__(256) void gemm_nt_hf(
    const _Float16* __restrict__ A, const float* __restrict__ Bm,
    const float* __restrict__ bias, float* __restrict__ C, int N)
{
    __shared__ __align__(16) _Float16 As[64][40];
    __shared__ __align__(16) _Float16 Bs[64][40];
    const int tid = threadIdx.x;
    const int w = tid >> 6, lane = tid & 63;
    const int m0 = blockIdx.y * 64, n0 = blockIdx.x * 64;
    const int srow = tid >> 2, sko = (tid & 3) * 8;
    const int fr = lane & 15, oct = lane >> 4;

    f32x4 acc[4];
#pragma unroll
    for (int nt = 0; nt < 4; ++nt) acc[nt] = (f32x4){0.f, 0.f, 0.f, 0.f};

    const bool bok = (n0 + srow) < N;
    const _Float16* ap = A + (size_t)(m0 + srow) * 512 + sko;
    const float* bp = Bm + (size_t)(n0 + srow) * 512 + sko;

    for (int k0 = 0; k0 < 512; k0 += 32) {
        half8 av = *(const half8*)(ap + k0);
        float4 b0 = make_float4(0.f, 0.f, 0.f, 0.f), b1 = b0;
        if (bok) { b0 = *(const float4*)(bp + k0); b1 = *(const float4*)(bp + k0 + 4); }
        __syncthreads();
        *(half8*)&As[srow][sko] = av;
        *(half8*)&Bs[srow][sko] = cvt8(b0, b1);
        __syncthreads();
        half8 af = *(const half8*)&As[w * 16 + fr][oct * 8];
#pragma unroll
        for (int nt = 0; nt < 4; ++nt) {
            half8 bf = *(const half8*)&Bs[nt * 16 + fr][oct * 8];
            acc[nt] = __builtin_amdgcn_mfma_f32_16x16x32_f16(af, bf, acc[nt], 0, 0, 0);
        }
    }
#pragma unroll
    for (int nt = 0; nt < 4; ++nt) {
        int nn = n0 + nt * 16 + fr;
        if (nn >= N) continue;
        float bb = bias[nn];
#pragma unroll
        for (int r = 0; r < 4; ++r) {
            int mm = m0 + w * 16 + oct * 4 + r;
            C[(size_t)mm * N + nn] = acc[nt][r] + bb;
        }
    }
}

// ---------------------------------------------------------------------------
// K_A (j-parallel, 256 blocks): block bid owns W_hh rows 8bid..8bid+7 and
// W_dec rows 2bid..2bid+1. Reads hT[j][b]; writes gH[b][row], dTb[b][j].
// ---------------------------------------------------------------------------
__global__ __launch_bounds__(256) void kA(
    const float* __restrict__ hT, const float* __restrict__ W_dec,
    const float* __restrict__ b_dec, const float* __restrict__ W_hh,
    float* __restrict__ dTb, float* __restrict__ gH)
{
    __shared__ __align__(16) float wpan[10 * 512];   // 20 KB
    __shared__ float red[4][640];                    // 10 KB
    const int tid = threadIdx.x, bid = blockIdx.x;
    const int lane = tid & 63, w = tid >> 6;

    for (int idx = tid * 4; idx < 10 * 512; idx += 1024) {
        int r = idx >> 9, k = idx & 511;
        const float* src = (r < 8) ? &W_hh[(size_t)(8 * bid + r) * 512 + k]
                                   : &W_dec[(size_t)(2 * bid + r - 8) * 512 + k];
        *(float4*)&wpan[idx] = *(const float4*)src;
    }
    __syncthreads();
    float acc[10] = {};
    for (int j4 = 32 * w; j4 < 32 * w + 32; ++j4) {
        int j = j4 * 4;
        float x0 = hT[(j + 0) * 64 + lane];
        float x1 = hT[(j + 1) * 64 + lane];
        float x2 = hT[(j + 2) * 64 + lane];
        float x3 = hT[(j + 3) * 64 + lane];
#pragma unroll
        for (int r = 0; r < 10; ++r) {
            float4 wv = *(const float4*)&wpan[r * 512 + j];
            acc[r] += wv.x * x0 + wv.y * x1 + wv.z * x2 + wv.w * x3;
        }
    }
#pragma unroll
    for (int r = 0; r < 10; ++r) red[w][r * 64 + lane] = acc[r];
    __syncthreads();
    for (int o = tid; o < 640; o += 256) {
        int r = o >> 6, b = o & 63;
        float s = red[0][o] + red[1][o] + red[2][o] + red[3][o];
        if (r < 8) gH[(size_t)b * 2048 + 8 * bid + r] = s;
        else       dTb[(size_t)b * 512 + 2 * bid + (r - 8)] = s + b_dec[2 * bid + r - 8];
    }
}

// ---------------------------------------------------------------------------
// K_B (b-parallel, 64 blocks): e/softmax/alpha; gates = sum_r alpha_r*G[b,r,:]
// + gH[b,:] + embg[b,t,:]; LSTM pointwise; writes cB, hT_next, Hh(f16).
// ---------------------------------------------------------------------------
__global__ __launch_bounds__(256) void kB(
    const float* __restrict__ dTb, const _Float16* __restrict__ encatH,
    const float* __restrict__ v_w, const float* __restrict__ v_b,
    const _Float16* __restrict__ G, const float* __restrict__ gH,
    const _Float16* __restrict__ embgH, float* __restrict__ cB,
    float* __restrict__ hTn, _Float16* __restrict__ Hh, int t)
{
    __shared__ float da[512];
    __shared__ float esh[52];
    __shared__ float al[52];
    __shared__ float gsm[2048];
    const int tid = threadIdx.x, b = blockIdx.x;
    const int lane = tid & 63, w = tid >> 6;

    da[tid]       = dTb[(size_t)b * 512 + tid];
    da[tid + 256] = dTb[(size_t)b * 512 + tid + 256];
    __syncthreads();

    for (int r = w; r < R_; r += 4) {
        const _Float16* er = encatH + ((size_t)b * R_ + r) * 512;
        float s = 0.f;
#pragma unroll
        for (int i = 0; i < 8; ++i) {
            int j = i * 64 + lane;
            s += ftanh((float)er[j] + da[j]) * v_w[j];
        }
#pragma unroll
        for (int off = 32; off; off >>= 1) s += __shfl_down(s, off, 64);
        if (lane == 0) esh[r] = s + v_b[0];
    }
    __syncthreads();
    if (tid < 64) {
        float x = (lane < R_) ? esh[lane] : -1e30f;
        float mx = x;
#pragma unroll
        for (int off = 32; off; off >>= 1) mx = fmaxf(mx, __shfl_xor(mx, off, 64));
        float ex = (lane < R_) ? __expf(x - mx) : 0.f;
        float sm = ex;
#pragma unroll
        for (int off = 32; off; off >>= 1) sm += __shfl_xor(sm, off, 64);
        if (lane < R_) al[lane] = ex / sm;
    }
    __syncthreads();

    // gates: rows [tid*8, tid*8+8)
    {
        const int r0 = tid * 8;
        float a8[8] = {};
        const _Float16* gp = G + ((size_t)b * R_) * 2048 + r0;
        for (int r = 0; r < R_; ++r) {
            half8 g8 = *(const half8*)(gp + (size_t)r * 2048);
            float ar = al[r];
#pragma unroll
            for (int u = 0; u < 8; ++u) a8[u] += ar * (float)g8[u];
        }
        float4 gh0 = *(const float4*)&gH[(size_t)b * 2048 + r0];
        float4 gh1 = *(const float4*)&gH[(size_t)b * 2048 + r0 + 4];
        half8 e8 = *(const half8*)&embgH[((size_t)b * TT + t) * 2048 + r0];
        gsm[r0 + 0] = a8[0] + gh0.x + (float)e8[0];
        gsm[r0 + 1] = a8[1] + gh0.y + (float)e8[1];
        gsm[r0 + 2] = a8[2] + gh0.z + (float)e8[2];
        gsm[r0 + 3] = a8[3] + gh0.w + (float)e8[3];
        gsm[r0 + 4] = a8[4] + gh1.x + (float)e8[4];
        gsm[r0 + 5] = a8[5] + gh1.y + (float)e8[5];
        gsm[r0 + 6] = a8[6] + gh1.z + (float)e8[6];
        gsm[r0 + 7] = a8[7] + gh1.w + (float)e8[7];
    }
    __syncthreads();

#pragma unroll
    for (int p = 0; p < 2; ++p) {
        int j = tid + p * 256;
        float ig = fsigm(gsm[j]);
        float fg = fsigm(gsm[512 + j]);
        float gg = ftanh(gsm[1024 + j]);
        float og = fsigm(gsm[1536 + j]);
        float c  = cB[(size_t)b * 512 + j];
        float cn = fg * c + ig * gg;
        float hn = og * ftanh(cn);
        cB[(size_t)b * 512 + j] = cn;
        hTn[(size_t)j * 64 + b] = hn;
        Hh[((size_t)b * TS + t) * 512 + j] = (_Float16)hn;
    }
}

// ---------------------------------------------------------------------------
extern "C" void kernel_launch(void* const* d_in, const int* in_sizes, int n_in,
                              void* d_out, int out_size, void* d_ws, size_t ws_size,
                              hipStream_t stream)
{
    (void)in_sizes; (void)n_in; (void)out_size; (void)ws_size;
    const float* feat     = (const float*)d_in[0];
    const float* caps     = (const float*)d_in[1];
    const float* W_enc    = (const float*)d_in[2];
    const float* b_enc    = (const float*)d_in[3];
    const float* W_dec    = (const float*)d_in[4];
    const float* b_dec    = (const float*)d_in[5];
    const float* v_w      = (const float*)d_in[6];
    const float* v_b      = (const float*)d_in[7];
    const float* W_ih     = (const float*)d_in[8];
    const float* W_hh     = (const float*)d_in[9];
    const float* b_ih     = (const float*)d_in[10];
    const float* b_hh     = (const float*)d_in[11];
    const float* W_init_h = (const float*)d_in[12];
    const float* b_init_h = (const float*)d_in[13];
    const float* W_init_c = (const float*)d_in[14];
    const float* b_init_c = (const float*)d_in[15];
    const float* W_out    = (const float*)d_in[16];
    const float* b_out    = (const float*)d_in[17];
    float* out = (float*)d_out;
    float* ws  = (float*)d_ws;

    // workspace layout (float slots): total 6,881,280 fl = 27.5 MB
    float* hT  = ws;                                   // 65,536  ping-pong [j][b]
    float* cB  = ws + 65536;                           // 32,768  [b][j]
    float* dTb = ws + 98304;                           // 32,768  [b][j]
    float* gH  = ws + 131072;                          // 131,072 [b][row]
    _Float16* encatH = (_Float16*)(ws + 262144);       // 3136*512 halves (802,816 fl)
    _Float16* embgH  = (_Float16*)(ws + 1064960);      // 2048*2048 halves (2,097,152 fl)
    _Float16* G      = (_Float16*)(ws + 3162112);      // 3136*2048 halves (3,211,264 fl)
    _Float16* Hh     = (_Float16*)(ws + 6373376);      // 1984*512 halves (507,904 fl)

    float* avg   = dTb;    // pre-phase alias (dead before decode)
    float* h0tmp = gH;     // pre-phase alias (32,768 <= 131,072)

    dim3 thr(256);

    // ---- pre-phase ----
    k_avg<<<128, thr, 0, stream>>>(feat, avg);
    gemm_nt_f32<<<dim3(8, 1), thr, 0, stream>>>(avg, 512, W_init_h, 512, b_init_h, nullptr,
                                                h0tmp, 512, 64, 512, 512);
    gemm_nt_f32<<<dim3(8, 1), thr, 0, stream>>>(avg, 512, W_init_c, 512, b_init_c, nullptr,
                                                cB, 512, 64, 512, 512);
    // embgH[b*32+t][row] = caps @ W_ih[:, :512]^T + b_ih + b_hh   (f16 out)
    gemm_nt_ff<<<dim3(32, 32), thr, 0, stream>>>(caps, 512, W_ih, 1024, b_ih, b_hh,
                                                 nullptr, embgH, 2048);
    // encatH[b*49+r][j] = feat @ W_enc^T + b_enc   (f16 out)
    gemm_nt_ff<<<dim3(8, 49), thr, 0, stream>>>(feat, 512, W_enc, 512, b_enc, nullptr,
                                                nullptr, encatH, 512);
    // G[b*49+r][row] = feat @ W_ih[:, 512:]^T   (f16 out, no bias)
    gemm_nt_ff<<<dim3(32, 49), thr, 0, stream>>>(feat, 512, W_ih + 512, 1024, nullptr, nullptr,
                                                 nullptr, G, 2048);
    k_tr<<<128, thr, 0, stream>>>(h0tmp, hT);    // h0 -> hT buffer 0

    // ---- decode: 2 launches per step ----
    for (int t = 0; t < TS; ++t) {
        const float* hR = hT + (size_t)(t & 1) * (H_ * 64);
        float*       hN = hT + (size_t)((t + 1) & 1) * (H_ * 64);
        kA<<<256, thr, 0, stream>>>(hR, W_dec, b_dec, W_hh, dTb, gH);
        kB<<<64, thr, 0, stream>>>(dTb, encatH, v_w, v_b, G, gH, embgH, cB, hN, Hh, t);
    }

    // ---- logits: Hh f16 x W_out fp32(cvt) -> out fp32 ----
    gemm_nt_hf<<<dim3(157, 31), thr, 0, stream>>>(Hh, W_out, b_out, out, V_);
}

// Round 10
// 1008.186 us; speedup vs baseline: 2.5170x; 1.0489x over previous
//
#include <hip/hip_runtime.h>
#include <cstddef>

// Problem dims
#define B_  64
#define R_  49
#define F_  512
#define H_  512
#define V_  10000
#define TT  32
#define TS  31

typedef _Float16 half8 __attribute__((ext_vector_type(8)));
typedef float    f32x4 __attribute__((ext_vector_type(4)));

__device__ __forceinline__ float fsigm(float x) { return 1.0f / (1.0f + __expf(-x)); }
__device__ __forceinline__ float ftanh(float x) { return 1.0f - 2.0f / (__expf(2.0f * x) + 1.0f); }

__device__ __forceinline__ half8 cvt8(float4 a, float4 b) {
    half8 o = { (_Float16)a.x, (_Float16)a.y, (_Float16)a.z, (_Float16)a.w,
                (_Float16)b.x, (_Float16)b.y, (_Float16)b.z, (_Float16)b.w };
    return o;
}

// ---------------------------------------------------------------------------
// Generic fp32 NT GEMM (h0/c0 only). Optional Ct: also store C^T with
// Ct[(size_t)n * ldct + m]  (used to write hT[j][b] directly for h0).
// ---------------------------------------------------------------------------
__global__ __launch_bounds__(256) void gemm_nt_f32(
    const float* __restrict__ A, int lda,
    const float* __restrict__ Bm, int ldb,
    const float* __restrict__ bias1, const float* __restrict__ bias2,
    float* __restrict__ C, int ldc, int M, int N, int K,
    float* __restrict__ Ct, int ldct)
{
    __shared__ __align__(16) float As[16][68];
    __shared__ __align__(16) float Bs[16][68];
    const int tid = threadIdx.x;
    const int m0 = blockIdx.y * 64, n0 = blockIdx.x * 64;
    const int tr = tid >> 4, tc = tid & 15;
    const int lrow = tid >> 2, lk4 = (tid & 3) * 4;
    const bool am = (m0 + lrow) < M;
    const bool bn = (n0 + lrow) < N;
    const float* aptr = A + (size_t)(m0 + lrow) * lda + lk4;
    const float* bptr = Bm + (size_t)(n0 + lrow) * ldb + lk4;
    float acc[4][4] = {};

    for (int k0 = 0; k0 < K; k0 += 16) {
        float4 av = make_float4(0.f, 0.f, 0.f, 0.f);
        float4 bv = make_float4(0.f, 0.f, 0.f, 0.f);
        if (am) av = *(const float4*)(aptr + k0);
        if (bn) bv = *(const float4*)(bptr + k0);
        __syncthreads();
        As[lk4 + 0][lrow] = av.x; As[lk4 + 1][lrow] = av.y;
        As[lk4 + 2][lrow] = av.z; As[lk4 + 3][lrow] = av.w;
        Bs[lk4 + 0][lrow] = bv.x; Bs[lk4 + 1][lrow] = bv.y;
        Bs[lk4 + 2][lrow] = bv.z; Bs[lk4 + 3][lrow] = bv.w;
        __syncthreads();
#pragma unroll
        for (int kk = 0; kk < 16; ++kk) {
            float4 a = *(const float4*)&As[kk][tr * 4];
            float4 b = *(const float4*)&Bs[kk][tc * 4];
            acc[0][0] += a.x * b.x; acc[0][1] += a.x * b.y; acc[0][2] += a.x * b.z; acc[0][3] += a.x * b.w;
            acc[1][0] += a.y * b.x; acc[1][1] += a.y * b.y; acc[1][2] += a.y * b.z; acc[1][3] += a.y * b.w;
            acc[2][0] += a.z * b.x; acc[2][1] += a.z * b.y; acc[2][2] += a.z * b.z; acc[2][3] += a.z * b.w;
            acc[3][0] += a.w * b.x; acc[3][1] += a.w * b.y; acc[3][2] += a.w * b.z; acc[3][3] += a.w * b.w;
        }
    }
#pragma unroll
    for (int i = 0; i < 4; ++i) {
        int m = m0 + tr * 4 + i;
        if (m >= M) continue;
#pragma unroll
        for (int j = 0; j < 4; ++j) {
            int n = n0 + tc * 4 + j;
            if (n >= N) continue;
            float v = acc[i][j];
            if (bias1) v += bias1[n];
            if (bias2) v += bias2[n];
            if (C)  C[(size_t)m * ldc + n] = v;
            if (Ct) Ct[(size_t)n * ldct + m] = v;
        }
    }
}

__global__ __launch_bounds__(256) void k_avg(const float* __restrict__ feat,
                                             float* __restrict__ avg)
{
    int id = blockIdx.x * 256 + threadIdx.x;
    int b = id >> 9, f = id & 511;
    const float* p = feat + (size_t)b * R_ * F_ + f;
    float s = 0.f;
#pragma unroll 7
    for (int r = 0; r < R_; ++r) s += p[r * F_];
    avg[id] = s * (1.0f / 49.0f);
}

// ---------------------------------------------------------------------------
// Mixed NT GEMM: A fp32 [M,512] (lda), B fp32 [N,512] (ldb), cvt->f16 in-kernel,
// MFMA 16x16x32, out f16 (Ch) or fp32 (Cf), + bias1 + bias2.
// ---------------------------------------------------------------------------
__global__ __launch_bounds__(256) void gemm_nt_ff(
    const float* __restrict__ A, int lda,
    const float* __restrict__ Bm, int ldb,
    const float* __restrict__ bias1, const float* __restrict__ bias2,
    float* __restrict__ Cf, _Float16* __restrict__ Ch, int N)
{
    __shared__ __align__(16) _Float16 As[64][40];
    __shared__ __align__(16) _Float16 Bs[64][40];
    const int tid = threadIdx.x;
    const int w = tid >> 6, lane = tid & 63;
    const int m0 = blockIdx.y * 64, n0 = blockIdx.x * 64;
    const int srow = tid >> 2, sko = (tid & 3) * 8;
    const int fr = lane & 15, oct = lane >> 4;

    f32x4 acc[4];
#pragma unroll
    for (int nt = 0; nt < 4; ++nt) acc[nt] = (f32x4){0.f, 0.f, 0.f, 0.f};

    const float* ap = A + (size_t)(m0 + srow) * lda + sko;
    const float* bp = Bm + (size_t)(n0 + srow) * ldb + sko;

    for (int k0 = 0; k0 < 512; k0 += 32) {
        float4 a0 = *(const float4*)(ap + k0);
        float4 a1 = *(const float4*)(ap + k0 + 4);
        float4 b0 = *(const float4*)(bp + k0);
        float4 b1 = *(const float4*)(bp + k0 + 4);
        __syncthreads();
        *(half8*)&As[srow][sko] = cvt8(a0, a1);
        *(half8*)&Bs[srow][sko] = cvt8(b0, b1);
        __syncthreads();
        half8 af = *(const half8*)&As[w * 16 + fr][oct * 8];
#pragma unroll
        for (int nt = 0; nt < 4; ++nt) {
            half8 bf = *(const half8*)&Bs[nt * 16 + fr][oct * 8];
            acc[nt] = __builtin_amdgcn_mfma_f32_16x16x32_f16(af, bf, acc[nt], 0, 0, 0);
        }
    }
#pragma unroll
    for (int nt = 0; nt < 4; ++nt) {
        int nn = n0 + nt * 16 + fr;
        float bb = bias1 ? bias1[nn] : 0.f;
        if (bias2) bb += bias2[nn];
#pragma unroll
        for (int r = 0; r < 4; ++r) {
            int mm = m0 + w * 16 + oct * 4 + r;
            float v = acc[nt][r] + bb;
            if (Cf) Cf[(size_t)mm * N + nn] = v;
            else    Ch[(size_t)mm * N + nn] = (_Float16)v;
        }
    }
}

// ---------------------------------------------------------------------------
// Logits GEMM, XCD-swizzled: A f16 [1984,512], B fp32 [N,512] cvt-in-kernel.
// 1D grid; xcd = L&7, g = L>>3, n_tile = xcd + 8*(g/31), m_tile = g%31.
// All 31 m-blocks of one n-tile run consecutively on ONE XCD -> its 256KB
// W_out panel is fetched once per XCD-L2 (B traffic ~20.5MB total, not 311MB).
// ---------------------------------------------------------------------------
#define MT_  31          // m-tiles (1984/64)
#define NT_  157         // n-tiles (ceil 10000/64)
__global__ __launch_bounds__(256) void gemm_nt_hf_swz(
    const _Float16* __restrict__ A, const float* __restrict__ Bm,
    const float* __restrict__ bias, float* __restrict__ C, int N)
{
    const int L = blockIdx.x;
    const int xcd = L & 7, g = L >> 3;
    const int ntile = xcd + 8 * (g / MT_);
    const int mtile = g % MT_;
    if (ntile >= NT_) return;

    __shared__ __align__(16) _Float16 As[64][40];
    __shared__ __align__(16) _Float16 Bs[64][40];
    const int tid = threadIdx.x;
    const int w = tid >> 6, lane = tid & 63;
    const int m0 = mtile * 64, n0 = ntile * 64;
    const int srow = tid >> 2, sko = (tid & 3) * 8;
    const int fr = lane & 15, oct = lane >> 4;

    f32x4 acc[4];
#pragma unroll
    for (int nt = 0; nt < 4; ++nt) acc[nt] = (f32x4){0.f, 0.f, 0.f, 0.f};

    const bool bok = (n0 + srow) < N;
    const _Float16* ap = A + (size_t)(m0 + srow) * 512 + sko;
    const float* bp = Bm + (size_t)(n0 + srow) * 512 + sko;

    for (int k0 = 0; k0 < 512; k0 += 32) {
        half8 av = *(const half8*)(ap + k0);
        float4 b0 = make_float4(0.f, 0.f, 0.f, 0.f), b1 = b0;
        if (bok) { b0 = *(const float4*)(bp + k0); b1 = *(const float4*)(bp + k0 + 4); }
        __syncthreads();
        *(half8*)&As[srow][sko] = av;
        *(half8*)&Bs[srow][sko] = cvt8(b0, b1);
        __syncthreads();
        half8 af = *(const half8*)&As[w * 16 + fr][oct * 8];
#pragma unroll
        for (int nt = 0; nt < 4; ++nt) {
            half8 bf = *(const half8*)&Bs[nt * 16 + fr][oct * 8];
            acc[nt] = __builtin_amdgcn_mfma_f32_16x16x32_f16(af, bf, acc[nt], 0, 0, 0);
        }
    }
#pragma unroll
    for (int nt = 0; nt < 4; ++nt) {
        int nn = n0 + nt * 16 + fr;
        if (nn >= N) continue;
        float bb = bias[nn];
#pragma unroll
        for (int r = 0; r < 4; ++r) {
            int mm = m0 + w * 16 + oct * 4 + r;
            C[(size_t)mm * N + nn] = acc[nt][r] + bb;
        }
    }
}

// ---------------------------------------------------------------------------
// K_A (j-parallel, 256 blocks): block bid owns W_hh rows 8bid..8bid+7 and
// W_dec rows 2bid..2bid+1. Reads hT[j][b]; writes gH[b][row], dTb[b][j].
// ---------------------------------------------------------------------------
__global__ __launch_bounds__(256) void kA(
    const float* __restrict__ hT, const float* __restrict__ W_dec,
    const float* __restrict__ b_dec, const float* __restrict__ W_hh,
    float* __restrict__ dTb, float* __restrict__ gH)
{
    __shared__ __align__(16) float wpan[10 * 512];   // 20 KB
    __shared__ float red[4][640];                    // 10 KB
    const int tid = threadIdx.x, bid = blockIdx.x;
    const int lane = tid & 63, w = tid >> 6;

    for (int idx = tid * 4; idx < 10 * 512; idx += 1024) {
        int r = idx >> 9, k = idx & 511;
        const float* src = (r < 8) ? &W_hh[(size_t)(8 * bid + r) * 512 + k]
                                   : &W_dec[(size_t)(2 * bid + r - 8) * 512 + k];
        *(float4*)&wpan[idx] = *(const float4*)src;
    }
    __syncthreads();
    float acc[10] = {};
    for (int j4 = 32 * w; j4 < 32 * w + 32; ++j4) {
        int j = j4 * 4;
        float x0 = hT[(j + 0) * 64 + lane];
        float x1 = hT[(j + 1) * 64 + lane];
        float x2 = hT[(j + 2) * 64 + lane];
        float x3 = hT[(j + 3) * 64 + lane];
#pragma unroll
        for (int r = 0; r < 10; ++r) {
            float4 wv = *(const float4*)&wpan[r * 512 + j];
            acc[r] += wv.x * x0 + wv.y * x1 + wv.z * x2 + wv.w * x3;
        }
    }
#pragma unroll
    for (int r = 0; r < 10; ++r) red[w][r * 64 + lane] = acc[r];
    __syncthreads();
    for (int o = tid; o < 640; o += 256) {
        int r = o >> 6, b = o & 63;
        float s = red[0][o] + red[1][o] + red[2][o] + red[3][o];
        if (r < 8) gH[(size_t)b * 2048 + 8 * bid + r] = s;
        else       dTb[(size_t)b * 512 + 2 * bid + (r - 8)] = s + b_dec[2 * bid + r - 8];
    }
}

// ---------------------------------------------------------------------------
// K_B (b-parallel, 64 blocks): e/softmax/alpha; gates = sum_r alpha_r*G[b,r,:]
// + gH[b,:] + embg[b,t,:]; LSTM pointwise; writes cB, hT_next, Hh(f16).
// ---------------------------------------------------------------------------
__global__ __launch_bounds__(256) void kB(
    const float* __restrict__ dTb, const _Float16* __restrict__ encatH,
    const float* __restrict__ v_w, const float* __restrict__ v_b,
    const _Float16* __restrict__ G, const float* __restrict__ gH,
    const _Float16* __restrict__ embgH, float* __restrict__ cB,
    float* __restrict__ hTn, _Float16* __restrict__ Hh, int t)
{
    __shared__ float da[512];
    __shared__ float esh[52];
    __shared__ float al[52];
    __shared__ float gsm[2048];
    const int tid = threadIdx.x, b = blockIdx.x;
    const int lane = tid & 63, w = tid >> 6;

    da[tid]       = dTb[(size_t)b * 512 + tid];
    da[tid + 256] = dTb[(size_t)b * 512 + tid + 256];
    __syncthreads();

    for (int r = w; r < R_; r += 4) {
        const _Float16* er = encatH + ((size_t)b * R_ + r) * 512;
        float s = 0.f;
#pragma unroll
        for (int i = 0; i < 8; ++i) {
            int j = i * 64 + lane;
            s += ftanh((float)er[j] + da[j]) * v_w[j];
        }
#pragma unroll
        for (int off = 32; off; off >>= 1) s += __shfl_down(s, off, 64);
        if (lane == 0) esh[r] = s + v_b[0];
    }
    __syncthreads();
    if (tid < 64) {
        float x = (lane < R_) ? esh[lane] : -1e30f;
        float mx = x;
#pragma unroll
        for (int off = 32; off; off >>= 1) mx = fmaxf(mx, __shfl_xor(mx, off, 64));
        float ex = (lane < R_) ? __expf(x - mx) : 0.f;
        float sm = ex;
#pragma unroll
        for (int off = 32; off; off >>= 1) sm += __shfl_xor(sm, off, 64);
        if (lane < R_) al[lane] = ex / sm;
    }
    __syncthreads();

    // gates: rows [tid*8, tid*8+8)
    {
        const int r0 = tid * 8;
        float a8[8] = {};
        const _Float16* gp = G + ((size_t)b * R_) * 2048 + r0;
        for (int r = 0; r < R_; ++r) {
            half8 g8 = *(const half8*)(gp + (size_t)r * 2048);
            float ar = al[r];
#pragma unroll
            for (int u = 0; u < 8; ++u) a8[u] += ar * (float)g8[u];
        }
        float4 gh0 = *(const float4*)&gH[(size_t)b * 2048 + r0];
        float4 gh1 = *(const float4*)&gH[(size_t)b * 2048 + r0 + 4];
        half8 e8 = *(const half8*)&embgH[((size_t)b * TT + t) * 2048 + r0];
        gsm[r0 + 0] = a8[0] + gh0.x + (float)e8[0];
        gsm[r0 + 1] = a8[1] + gh0.y + (float)e8[1];
        gsm[r0 + 2] = a8[2] + gh0.z + (float)e8[2];
        gsm[r0 + 3] = a8[3] + gh0.w + (float)e8[3];
        gsm[r0 + 4] = a8[4] + gh1.x + (float)e8[4];
        gsm[r0 + 5] = a8[5] + gh1.y + (float)e8[5];
        gsm[r0 + 6] = a8[6] + gh1.z + (float)e8[6];
        gsm[r0 + 7] = a8[7] + gh1.w + (float)e8[7];
    }
    __syncthreads();

#pragma unroll
    for (int p = 0; p < 2; ++p) {
        int j = tid + p * 256;
        float ig = fsigm(gsm[j]);
        float fg = fsigm(gsm[512 + j]);
        float gg = ftanh(gsm[1024 + j]);
        float og = fsigm(gsm[1536 + j]);
        float c  = cB[(size_t)b * 512 + j];
        float cn = fg * c + ig * gg;
        float hn = og * ftanh(cn);
        cB[(size_t)b * 512 + j] = cn;
        hTn[(size_t)j * 64 + b] = hn;
        Hh[((size_t)b * TS + t) * 512 + j] = (_Float16)hn;
    }
}

// ---------------------------------------------------------------------------
extern "C" void kernel_launch(void* const* d_in, const int* in_sizes, int n_in,
                              void* d_out, int out_size, void* d_ws, size_t ws_size,
                              hipStream_t stream)
{
    (void)in_sizes; (void)n_in; (void)out_size; (void)ws_size;
    const float* feat     = (const float*)d_in[0];
    const float* caps     = (const float*)d_in[1];
    const float* W_enc    = (const float*)d_in[2];
    const float* b_enc    = (const float*)d_in[3];
    const float* W_dec    = (const float*)d_in[4];
    const float* b_dec    = (const float*)d_in[5];
    const float* v_w      = (const float*)d_in[6];
    const float* v_b      = (const float*)d_in[7];
    const float* W_ih     = (const float*)d_in[8];
    const float* W_hh     = (const float*)d_in[9];
    const float* b_ih     = (const float*)d_in[10];
    const float* b_hh     = (const float*)d_in[11];
    const float* W_init_h = (const float*)d_in[12];
    const float* b_init_h = (const float*)d_in[13];
    const float* W_init_c = (const float*)d_in[14];
    const float* b_init_c = (const float*)d_in[15];
    const float* W_out    = (const float*)d_in[16];
    const float* b_out    = (const float*)d_in[17];
    float* out = (float*)d_out;
    float* ws  = (float*)d_ws;

    // workspace layout (float slots): total 6,881,280 fl = 27.5 MB (as R9)
    float* hT  = ws;                                   // 65,536  ping-pong [j][b]
    float* cB  = ws + 65536;                           // 32,768  [b][j]
    float* dTb = ws + 98304;                           // 32,768  [b][j]
    float* gH  = ws + 131072;                          // 131,072 [b][row]
    _Float16* encatH = (_Float16*)(ws + 262144);       // 3136*512 halves
    _Float16* embgH  = (_Float16*)(ws + 1064960);      // 2048*2048 halves
    _Float16* G      = (_Float16*)(ws + 3162112);      // 3136*2048 halves
    _Float16* Hh     = (_Float16*)(ws + 6373376);      // 1984*512 halves

    float* avg = dTb;    // pre-phase alias (dead before decode)

    dim3 thr(256);

    // ---- pre-phase ----
    k_avg<<<128, thr, 0, stream>>>(feat, avg);
    // h0: write hT[j][b] directly via transposed store (no k_tr)
    gemm_nt_f32<<<dim3(8, 1), thr, 0, stream>>>(avg, 512, W_init_h, 512, b_init_h, nullptr,
                                                nullptr, 0, 64, 512, 512, hT, 64);
    gemm_nt_f32<<<dim3(8, 1), thr, 0, stream>>>(avg, 512, W_init_c, 512, b_init_c, nullptr,
                                                cB, 512, 64, 512, 512, nullptr, 0);
    // embgH[b*32+t][row] = caps @ W_ih[:, :512]^T + b_ih + b_hh   (f16 out)
    gemm_nt_ff<<<dim3(32, 32), thr, 0, stream>>>(caps, 512, W_ih, 1024, b_ih, b_hh,
                                                 nullptr, embgH, 2048);
    // encatH[b*49+r][j] = feat @ W_enc^T + b_enc   (f16 out)
    gemm_nt_ff<<<dim3(8, 49), thr, 0, stream>>>(feat, 512, W_enc, 512, b_enc, nullptr,
                                                nullptr, encatH, 512);
    // G[b*49+r][row] = feat @ W_ih[:, 512:]^T   (f16 out, no bias)
    gemm_nt_ff<<<dim3(32, 49), thr, 0, stream>>>(feat, 512, W_ih + 512, 1024, nullptr, nullptr,
                                                 nullptr, G, 2048);

    // ---- decode: 2 launches per step ----
    for (int t = 0; t < TS; ++t) {
        const float* hR = hT + (size_t)(t & 1) * (H_ * 64);
        float*       hN = hT + (size_t)((t + 1) & 1) * (H_ * 64);
        kA<<<256, thr, 0, stream>>>(hR, W_dec, b_dec, W_hh, dTb, gH);
        kB<<<64, thr, 0, stream>>>(dTb, encatH, v_w, v_b, G, gH, embgH, cB, hN, Hh, t);
    }

    // ---- logits: XCD-swizzled f16 MFMA GEMM ----
    // grid: 8 xcd-lanes x 620 = 4960 blocks (guarded); n = xcd+8k, m = g%31
    gemm_nt_hf_swz<<<4960, thr, 0, stream>>>(Hh, W_out, b_out, out, V_);
}